// Round 2
// baseline (22912.970 us; speedup 1.0000x reference)
//
#include <hip/hip_runtime.h>
#include <hip/hip_bf16.h>
#include <hip/hip_cooperative_groups.h>

namespace cg = cooperative_groups;

typedef __hip_bfloat16 bf16;
typedef __attribute__((ext_vector_type(8))) short bf16x8;   // MFMA A/B frag (8 bf16)
typedef __attribute__((ext_vector_type(4))) short bf16x4;
typedef __attribute__((ext_vector_type(4))) float f32x4;    // MFMA C/D frag

__device__ __forceinline__ float ldE(const float* p) { return *p; }
__device__ __forceinline__ float ldE(const bf16* p)  { return (float)*p; }
__device__ __forceinline__ void stC(float* p, float v) { *p = v; }
__device__ __forceinline__ void stC(bf16* p, float v)  { *p = __float2bfloat16(v); }

__device__ __forceinline__ short f2s(float f) {
    bf16 b = __float2bfloat16(f);
    return __builtin_bit_cast(short, b);
}

// NaN-proof activations (clamp = no-op on sane data, sanitizes garbage).
__device__ __forceinline__ float sigm(float x) {
    x = fminf(fmaxf(x, -40.f), 40.f);
    return 1.f / (1.f + expf(-x));
}
__device__ __forceinline__ float tanh_s(float x) {
    x = fminf(fmaxf(x, -20.f), 20.f);
    float e = expf(2.f * x);
    return 1.f - 2.f / (e + 1.f);
}

// 16B-aligned 8-element loads -> bf16x8
__device__ __forceinline__ bf16x8 ld8(const bf16* p) {
    return *reinterpret_cast<const bf16x8*>(p);
}
__device__ __forceinline__ bf16x8 ld8(const float* p) {
    const float4 f0 = *reinterpret_cast<const float4*>(p);
    const float4 f1 = *reinterpret_cast<const float4*>(p + 4);
    bf16x8 v;
    v[0] = f2s(f0.x); v[1] = f2s(f0.y); v[2] = f2s(f0.z); v[3] = f2s(f0.w);
    v[4] = f2s(f1.x); v[5] = f2s(f1.y); v[6] = f2s(f1.z); v[7] = f2s(f1.w);
    return v;
}
// 8B-aligned 8-element load (rows with odd*8B stride)
__device__ __forceinline__ bf16x8 ld8_8B(const bf16* p) {
    bf16x4 lo = *reinterpret_cast<const bf16x4*>(p);
    bf16x4 hi = *reinterpret_cast<const bf16x4*>(p + 4);
    bf16x8 v;
    v[0] = lo[0]; v[1] = lo[1]; v[2] = lo[2]; v[3] = lo[3];
    v[4] = hi[0]; v[5] = hi[1]; v[6] = hi[2]; v[7] = hi[3];
    return v;
}

// f32 -> bf16 bulk convert
__global__ void f2b(const float* __restrict__ src, bf16* __restrict__ dst, long n) {
    long i = (long)blockIdx.x * 256 + threadIdx.x;
    if (i < n) dst[i] = __float2bfloat16(src[i]);
}

// ============================ MFMA GEMM ============================
// C[d] = A[d] (MxK row-major) @ W[d]^T (W is NcxK row-major f32, converted to
// bf16 in staging). BM=128 BN=64 BK=32, 256 thr = 4 waves.
#define MBM 128
#define MBN 64
#define MLD 40   // padded LDS row stride in bf16 (80B)

template <typename AT, typename CT, bool VEC>
__global__ __launch_bounds__(256) void gemm_mfma(
    const AT* __restrict__ A, long sAd,
    const float* __restrict__ W, long sWd,
    CT* __restrict__ C, long sCd,
    int M, int Nc, int K)
{
    __shared__ bf16 As[MBM * MLD];
    __shared__ bf16 Ws[MBN * MLD];
    const int d = blockIdx.z;
    A += (long)d * sAd; W += (long)d * sWd; C += (long)d * sCd;
    const int m0 = blockIdx.y * MBM;
    const int n0 = blockIdx.x * MBN;
    const int tid = threadIdx.x;
    const int w = tid >> 6, l = tid & 63;
    const int lr = l & 15, lq = l >> 4;

    f32x4 acc[2][4] = {};

    for (int k0 = 0; k0 < K; k0 += 32) {
        if (VEC) {
#pragma unroll
            for (int i = 0; i < 2; ++i) {
                int u = tid + i * 256;
                int r = u >> 2, kk = (u & 3) * 8;
                bf16x8 v = {};
                if (m0 + r < M && k0 + kk < K)       // K%8==0: in -> all 8 in
                    v = ld8(A + (long)(m0 + r) * K + k0 + kk);
                *reinterpret_cast<bf16x8*>(&As[r * MLD + kk]) = v;
            }
            {
                int r = tid >> 2, kk = (tid & 3) * 8;
                bf16x8 v = {};
                if (n0 + r < Nc && k0 + kk < K)
                    v = ld8(W + (long)(n0 + r) * K + k0 + kk);
                *reinterpret_cast<bf16x8*>(&Ws[r * MLD + kk]) = v;
            }
        } else {
#pragma unroll
            for (int i = 0; i < 8; ++i) {
                int u = tid + i * 256;
                int r = u >> 4, kk = (u & 15) * 2;
                float v0 = 0.f, v1 = 0.f;
                if (m0 + r < M) {
                    const AT* p = A + (long)(m0 + r) * K + k0 + kk;
                    if (k0 + kk < K)     v0 = ldE(p);
                    if (k0 + kk + 1 < K) v1 = ldE(p + 1);
                }
                As[r * MLD + kk]     = __float2bfloat16(v0);
                As[r * MLD + kk + 1] = __float2bfloat16(v1);
            }
#pragma unroll
            for (int i = 0; i < 4; ++i) {
                int u = tid + i * 256;
                int r = u >> 4, kk = (u & 15) * 2;
                float v0 = 0.f, v1 = 0.f;
                if (n0 + r < Nc) {
                    const float* p = W + (long)(n0 + r) * K + k0 + kk;
                    if (k0 + kk < K)     v0 = *p;
                    if (k0 + kk + 1 < K) v1 = *(p + 1);
                }
                Ws[r * MLD + kk]     = __float2bfloat16(v0);
                Ws[r * MLD + kk + 1] = __float2bfloat16(v1);
            }
        }
        __syncthreads();
        bf16x8 af[2], bw[4];
        af[0] = *reinterpret_cast<const bf16x8*>(&As[(w * 32 + lr) * MLD + lq * 8]);
        af[1] = *reinterpret_cast<const bf16x8*>(&As[(w * 32 + 16 + lr) * MLD + lq * 8]);
#pragma unroll
        for (int ni = 0; ni < 4; ++ni)
            bw[ni] = *reinterpret_cast<const bf16x8*>(&Ws[(ni * 16 + lr) * MLD + lq * 8]);
#pragma unroll
        for (int mi = 0; mi < 2; ++mi)
#pragma unroll
            for (int ni = 0; ni < 4; ++ni)
                acc[mi][ni] = __builtin_amdgcn_mfma_f32_16x16x32_bf16(
                    af[mi], bw[ni], acc[mi][ni], 0, 0, 0);
        __syncthreads();
    }
    // D layout: col = lane&15, row = (lane>>4)*4 + reg
#pragma unroll
    for (int mi = 0; mi < 2; ++mi) {
#pragma unroll
        for (int reg = 0; reg < 4; ++reg) {
            int m = m0 + w * 32 + mi * 16 + lq * 4 + reg;
            if (m >= M) continue;
#pragma unroll
            for (int ni = 0; ni < 4; ++ni) {
                int n = n0 + ni * 16 + lr;
                if (n < Nc) stC(&C[(long)m * Nc + n], acc[mi][ni][reg]);
            }
        }
    }
}

// ============= persistent cooperative sentence GRU (MFMA) =============
// One cooperative launch runs CH=60 steps. Grid (44 j-tiles, 4 m-tiles, 2
// dirs) = 352 blocks x 128 thr, 2 waves; wave w owns batch rows
// mt*32 + w*16 + [0,16). Whh B-fragments for the block's 16-col j-tile
// (3 gates x 22 k-steps) are staged ONCE into LDS (67.6 KB -> 2 blocks/CU,
// co-residency 512 >= 352), pre-arranged in exact MFMA fragment order so
// ds_read_b128 is conflict-free. Per step: all 22 A-frags issued up front
// (deep MLP), xw gates prefetched (h-independent), MFMA, fused gate epilogue,
// ping-pong h_bf swap, grid.sync().
#define NKS 22   // ceil(700/32)
#define HBPE (2 * 128 * 700)   // ping stride in elems

__global__ __launch_bounds__(128) void gru_sent_persist(
    const bf16* __restrict__ Whh,   // [2,2100,700] bf16
    const bf16* __restrict__ xw,    // [2,Cbuf,128,2100] bf16
    int tb0, int tb1, int Cbuf,
    const float* __restrict__ bih,  // [2,2100]
    const float* __restrict__ bhh,  // [2,2100]
    float* __restrict__ h,          // [2,128,700] f32 master
    bf16* __restrict__ hbf,         // 2 pings x [2,128,700]
    bf16* __restrict__ y,           // [L,128,1400] or nullptr
    int L, int k_begin, int k_end)
{
    extern __shared__ bf16 Wlds[];  // [NKS][3][64][8] = 67,584 B
    const int jt = blockIdx.x, mt = blockIdx.y, d = blockIdx.z;
    const int tid = threadIdx.x;
    const int w = tid >> 6, l = tid & 63;
    const int lr = l & 15, lq = l >> 4;
    const int j0 = jt * 16;

    // ---- stage Whh fragments to LDS (once per launch) ----
    // unit u = (kk*3+g)*64 + lane ; global row = g*700 + j0 + (lane&15),
    // k = kk*32 + (lane>>4)*8. Zero-pad rows>=700 and k>=700.
    const bf16* Wd = Whh + (long)d * 2100 * 700;
    for (int u = tid; u < NKS * 3 * 64; u += 128) {
        int lane = u & 63;
        int g = (u >> 6) % 3;
        int kk = u / (3 * 64);
        int row = j0 + (lane & 15);
        int k = kk * 32 + (lane >> 4) * 8;
        bf16x8 v = {};
        if (row < 700) {
            const bf16* p = Wd + (long)(g * 700 + row) * 700 + k;
            if (k + 8 <= 700) {
                v = ld8_8B(p);
            } else {
#pragma unroll
                for (int i = 0; i < 8; ++i)
                    if (k + i < 700) v[i] = __builtin_bit_cast(short, p[i]);
            }
        }
        *reinterpret_cast<bf16x8*>(&Wlds[u * 8]) = v;
    }
    __syncthreads();

    const int arow = mt * 32 + w * 16 + lr;          // A-frag batch row (<128)
    const long aoff = ((long)d * 128 + arow) * 700;
    const int jcol = j0 + lr;
    const bool jok = jcol < 700;

    // hoisted biases (jcol<=703 < 2100: safe to load unconditionally)
    const float bir = bih[d * 2100 + jcol];
    const float biz = bih[d * 2100 + 700 + jcol];
    const float bin = bih[d * 2100 + 1400 + jcol];
    const float bhr = bhh[d * 2100 + jcol];
    const float bhz = bhh[d * 2100 + 700 + jcol];
    const float bhn = bhh[d * 2100 + 1400 + jcol];

    cg::grid_group grid = cg::this_grid();

    for (int k = k_begin; k < k_end; ++k) {
        const int p = k & 1;
        const bf16* Ab = hbf + (long)p * HBPE + aoff;        // read ping
        bf16* hw = hbf + (long)(p ^ 1) * HBPE;               // write pong

        const int t_eff = (d == 0) ? k : (L - 1 - k);
        const int tl = t_eff - ((d == 0) ? tb0 : tb1);
        const bf16* xbase = xw + ((long)d * Cbuf + tl) * 128 * 2100;

        // prefetch xw gates (independent of h) — issued before MFMA phase
        bf16 xg[3][4];
#pragma unroll
        for (int reg = 0; reg < 4; ++reg) {
            const int m = mt * 32 + w * 16 + lq * 4 + reg;
            const bf16* xp = xbase + (long)m * 2100 + jcol;
#pragma unroll
            for (int g = 0; g < 3; ++g) xg[g][reg] = xp[g * 700];
        }

        // load all 22 A-frags (44 x 8B loads in flight)
        bf16x8 areg[NKS];
#pragma unroll
        for (int kk = 0; kk < NKS; ++kk) {
            const int kb = kk * 32 + lq * 8;
            if (kb + 8 <= 700) {
                areg[kk] = ld8_8B(Ab + kb);
            } else {                                  // kb = 696: 4 valid elems
                bf16x8 v = {};
                bf16x4 lo = *reinterpret_cast<const bf16x4*>(Ab + kb);
                v[0] = lo[0]; v[1] = lo[1]; v[2] = lo[2]; v[3] = lo[3];
                areg[kk] = v;
            }
        }

        f32x4 acc[3] = {};
#pragma unroll
        for (int kk = 0; kk < NKS; ++kk) {
#pragma unroll
            for (int g = 0; g < 3; ++g) {
                bf16x8 b = *reinterpret_cast<const bf16x8*>(
                    &Wlds[((kk * 3 + g) * 64 + l) * 8]);
                acc[g] = __builtin_amdgcn_mfma_f32_16x16x32_bf16(
                    areg[kk], b, acc[g], 0, 0, 0);
            }
        }

        if (jok) {
#pragma unroll
            for (int reg = 0; reg < 4; ++reg) {
                const int m = mt * 32 + w * 16 + lq * 4 + reg;   // D row = batch
                float r  = sigm((float)xg[0][reg] + bir + acc[0][reg] + bhr);
                float z  = sigm((float)xg[1][reg] + biz + acc[1][reg] + bhz);
                float nn = tanh_s((float)xg[2][reg] + bin + r * (acc[2][reg] + bhn));
                const long hidx = ((long)d * 128 + m) * 700 + jcol;
                const float hnew = (1.f - z) * nn + z * h[hidx];
                h[hidx] = hnew;
                hw[hidx] = __float2bfloat16(hnew);
                if (y) y[((long)t_eff * 128 + m) * 1400 + (long)d * 700 + jcol] =
                           __float2bfloat16(hnew);
            }
        }
        __threadfence();   // release: make hw visible device-wide
        grid.sync();
        __threadfence();   // acquire: don't read stale pong from local caches
    }
}

// Word layer-0 GRU step: input gates gathered from embW[tok] (= emb @ Wih0^T).
__global__ void gru_step_word0(
    const int* __restrict__ x,      // [S,T,B]
    const bf16* __restrict__ embW,  // [2, V, 3H]
    const float* __restrict__ gh,   // [2, N, 3H]
    const float* __restrict__ bih,
    const float* __restrict__ bhh,
    float* __restrict__ h,          // [2, N, H]
    bf16* __restrict__ y,           // [T, N, 2H]
    int S, int T, int B, int V, int H, int k)
{
    const int N = S * B;
    long idx = (long)blockIdx.x * 256 + threadIdx.x;
    if (idx >= 2ll * N * H) return;
    int j = idx % H;
    int n = (idx / H) % N;
    int d = idx / ((long)N * H);
    int G = 3 * H;
    int t_eff = (d == 0) ? k : (T - 1 - k);
    int s = n / B, b = n % B;
    int tok = x[((long)s * T + t_eff) * B + b];
    tok = max(0, min(V - 1, tok));

    const bf16*  xp = embW + ((long)d * V + tok) * G;
    const float* gp = gh + ((long)d * N + n) * G;
    const float* bi = bih + (long)d * G;
    const float* bh = bhh + (long)d * G;

    float xr = (float)xp[j]         + bi[j];
    float xz = (float)xp[H + j]     + bi[H + j];
    float xn = (float)xp[2 * H + j] + bi[2 * H + j];
    float hr = gp[j]         + bh[j];
    float hz = gp[H + j]     + bh[H + j];
    float hn = gp[2 * H + j] + bh[2 * H + j];

    float r = sigm(xr + hr);
    float z = sigm(xz + hz);
    float nn = tanh_s(xn + r * hn);

    long hidx = ((long)d * N + n) * H + j;
    float hnew = (1.f - z) * nn + z * h[hidx];
    h[hidx] = hnew;
    y[((long)t_eff * N + n) * (2 * H) + (long)d * H + j] = __float2bfloat16(hnew);
}

// Generic GRU step (word layer 1). xw layout [2, Cbuf, N, 3H].
__global__ void gru_step1(
    const bf16* __restrict__ xw,
    int tb0, int tb1, int Cbuf,
    const float* __restrict__ gh,
    const float* __restrict__ bih,
    const float* __restrict__ bhh,
    float* __restrict__ h,
    bf16* __restrict__ y,
    int N, int H, int L, int k)
{
    long idx = (long)blockIdx.x * 256 + threadIdx.x;
    if (idx >= 2ll * N * H) return;
    int j = idx % H;
    int n = (idx / H) % N;
    int d = idx / ((long)N * H);
    int G = 3 * H;
    int t_eff = (d == 0) ? k : (L - 1 - k);
    int t_local = t_eff - ((d == 0) ? tb0 : tb1);

    const bf16*  xp = xw + (((long)d * Cbuf + t_local) * N + n) * G;
    const float* gp = gh + ((long)d * N + n) * G;
    const float* bi = bih + (long)d * G;
    const float* bh = bhh + (long)d * G;

    float xr = (float)xp[j]         + bi[j];
    float xz = (float)xp[H + j]     + bi[H + j];
    float xn = (float)xp[2 * H + j] + bi[2 * H + j];
    float hr = gp[j]         + bh[j];
    float hz = gp[H + j]     + bh[H + j];
    float hn = gp[2 * H + j] + bh[2 * H + j];

    float r = sigm(xr + hr);
    float z = sigm(xz + hz);
    float nn = tanh_s(xn + r * hn);

    long hidx = ((long)d * N + n) * H + j;
    float hnew = (1.f - z) * nn + z * h[hidx];
    h[hidx] = hnew;
    if (y) y[((long)t_eff * N + n) * (2 * H) + (long)d * H + j] = __float2bfloat16(hnew);
}

// out[n, 4H] = [ha_d0 | ha_d1 | hb_d0 | hb_d1]
template <typename OT>
__global__ void concat4(const float* __restrict__ ha, const float* __restrict__ hb,
                        OT* __restrict__ out, int N, int H)
{
    long idx = (long)blockIdx.x * 256 + threadIdx.x;
    int C4 = 4 * H;
    if (idx >= (long)N * C4) return;
    int c = idx % C4;
    long n = idx / C4;
    int blk = c / H, j = c % H;
    const float* src = (blk < 2) ? ha : hb;
    int dd = blk & 1;
    stC(&out[idx], src[((long)dd * N + n) * H + j]);
}

extern "C" void kernel_launch(void* const* d_in, const int* in_sizes, int n_in,
                              void* d_out, int out_size, void* d_ws, size_t ws_size,
                              hipStream_t stream)
{
    const int S = 120, T = 10, B = 128, E = 80, HW = 75, HS = 700, V = 30000;
    const int Nw = S * B;            // 15360
    const int Gw = 3 * HW;           // 225
    const int Gs = 3 * HS;           // 2100
    const int CH = 60;               // sentence chunk size
    (void)in_sizes; (void)n_in; (void)out_size; (void)ws_size;

    const int*   x       = (const int*)d_in[0];
    const float* emb     = (const float*)d_in[1];
    const float* we_Wih0 = (const float*)d_in[2],  *we_Whh0 = (const float*)d_in[3];
    const float* we_bih0 = (const float*)d_in[4],  *we_bhh0 = (const float*)d_in[5];
    const float* we_Wih1 = (const float*)d_in[6],  *we_Whh1 = (const float*)d_in[7];
    const float* we_bih1 = (const float*)d_in[8],  *we_bhh1 = (const float*)d_in[9];
    const float* se_Wih0 = (const float*)d_in[10], *se_Whh0 = (const float*)d_in[11];
    const float* se_bih0 = (const float*)d_in[12], *se_bhh0 = (const float*)d_in[13];
    const float* se_Wih1 = (const float*)d_in[14], *se_Whh1 = (const float*)d_in[15];
    const float* se_bih1 = (const float*)d_in[16], *se_bhh1 = (const float*)d_in[17];

    // ---- arenas (142.2 MB total; proven-safe < 149 MB) ----
    char* ws = (char*)d_ws;
    const size_t szA = 9216000;    // words bf16 [Nw,300]
    const size_t szB = 46080000;   // y0w bf16 [T*Nw,150] -> y0s bf16 [S*B,1400]=43.0MB
    const size_t szCDE = 68472000; // word: embW 27.0 | gh_w 27.648 | xw_w1 13.824
                                   // sent: xw_chunk bf16 [2,CH,B,Gs] = 64.512MB
    const size_t szF = 9216000;    // h_w0 -> Whh0_bf 5.88 | hbf0 pings 0.7168
    const size_t szG = 9216000;    // h_w1 -> h_s0|h_s1 1.4336 | Whh1_bf 5.88 | hbf1 0.7168
    char* pA = ws;
    char* pB = pA + szA;
    char* pC = pB + szB;
    char* pF = pC + szCDE;
    char* pG = pF + szF;
    const size_t total = szA + szB + szCDE + szF + szG;  // 142,200,000

    bf16*  words  = (bf16*)pA;
    bf16*  y0w    = (bf16*)pB;
    bf16*  y0s    = (bf16*)pB;
    bf16*  embW   = (bf16*)pC;                       // word phase
    float* gh_w   = (float*)(pC + 27000000);
    bf16*  xw_w1  = (bf16*)(pC + 27000000 + 27648000);
    bf16*  xw_ch  = (bf16*)pC;                       // sentence phase (overlays)
    float* h_w0   = (float*)pF;
    float* h_w1   = (float*)pG;
    // sentence-phase overlays (word buffers dead after concat4)
    bf16*  Whh0b  = (bf16*)pF;                       // [2,2100,700] bf16 = 5,880,000B
    bf16*  hbf0   = (bf16*)(pF + 5880000);           // 2 pings x 358,400B
    float* h_s0   = (float*)pG;                      // 716,800B
    float* h_s1   = (float*)(pG + 716800);           // 716,800B
    bf16*  Whh1b  = (bf16*)(pG + 1433600);           // 5,880,000B
    bf16*  hbf1   = (bf16*)(pG + 7313600);           // 716,800B

    hipMemsetAsync(ws, 0, total, stream);  // poison kill + h0 = 0

    // ===================== word encoder =====================
    // embW[d] = emb @ Wih0[d]^T : [V,80] @ [225,80]^T -> [2,V,225]  (K=80: VEC)
    gemm_mfma<float, bf16, true><<<dim3((Gw + MBN - 1) / MBN, (V + MBM - 1) / MBM, 2),
                                   256, 0, stream>>>(
        emb, 0, we_Wih0, (long)Gw * E, embW, (long)V * Gw, V, Gw, E);
    // ---- layer 0 ----
    for (int k = 0; k < T; ++k) {
        gemm_mfma<float, float, false><<<dim3((Gw + MBN - 1) / MBN, (Nw + MBM - 1) / MBM, 2),
                                         256, 0, stream>>>(
            h_w0, (long)Nw * HW, we_Whh0, (long)Gw * HW, gh_w, (long)Nw * Gw, Nw, Gw, HW);
        long tot = 2ll * Nw * HW;
        gru_step_word0<<<(tot + 255) / 256, 256, 0, stream>>>(
            x, embW, gh_w, we_bih0, we_bhh0, h_w0, y0w, S, T, B, V, HW, k);
    }
    // ---- layer 1 ----
    for (int k = 0; k < T; ++k) {
        gemm_mfma<bf16, bf16, false><<<dim3((Gw + MBN - 1) / MBN, (Nw + MBM - 1) / MBM, 2),
                                       256, 0, stream>>>(
            y0w + (long)k * Nw * 2 * HW, (long)(T - 1 - 2 * k) * Nw * 2 * HW,
            we_Wih1, (long)Gw * (2 * HW), xw_w1, (long)Nw * Gw, Nw, Gw, 2 * HW);
        gemm_mfma<float, float, false><<<dim3((Gw + MBN - 1) / MBN, (Nw + MBM - 1) / MBM, 2),
                                         256, 0, stream>>>(
            h_w1, (long)Nw * HW, we_Whh1, (long)Gw * HW, gh_w, (long)Nw * Gw, Nw, Gw, HW);
        long tot = 2ll * Nw * HW;
        gru_step1<<<(tot + 255) / 256, 256, 0, stream>>>(
            xw_w1, k, T - 1 - k, 1, gh_w, we_bih1, we_bhh1, h_w1, nullptr, Nw, HW, T, k);
    }
    {
        long tot = (long)Nw * 4 * HW;
        concat4<bf16><<<(tot + 255) / 256, 256, 0, stream>>>(h_w0, h_w1, words, Nw, HW);
    }

    // ===================== sentence encoder =====================
    // Whh -> bf16 (once); zero recurrent states (regions overlay word h's).
    {
        long nwh = 2LL * Gs * HS;  // 2,940,000
        f2b<<<(nwh + 255) / 256, 256, 0, stream>>>(se_Whh0, Whh0b, nwh);
        f2b<<<(nwh + 255) / 256, 256, 0, stream>>>(se_Whh1, Whh1b, nwh);
    }
    hipMemsetAsync(h_s0, 0, 2 * 716800, stream);   // h_s0 + h_s1
    hipMemsetAsync(hbf0, 0, 716800, stream);       // both pings
    hipMemsetAsync(hbf1, 0, 716800, stream);

    const unsigned ldsBytes = (unsigned)(NKS * 3 * 64 * 8 * sizeof(bf16)); // 67,584

    // ---- layer 0: 2 chunks of 60 steps; xw batched per chunk (K=300) ----
    for (int c = 0; c < 2; ++c) {
        int tb0 = c * CH;
        int tb1 = S - c * CH - CH;
        gemm_mfma<bf16, bf16, false><<<dim3((Gs + MBN - 1) / MBN, (CH * B + MBM - 1) / MBM, 2),
                                       256, 0, stream>>>(
            words + (long)tb0 * B * (4 * HW), (long)(tb1 - tb0) * B * (4 * HW),
            se_Wih0, (long)Gs * (4 * HW), xw_ch, (long)CH * B * Gs, CH * B, Gs, 4 * HW);
        {
            const bf16* Whh_ = Whh0b; const bf16* xw_ = xw_ch;
            int tb0_ = tb0, tb1_ = tb1, cb_ = CH;
            const float* bih_ = se_bih0; const float* bhh_ = se_bhh0;
            float* h_ = h_s0; bf16* hbf_ = hbf0; bf16* y_ = y0s;
            int L_ = S, kb_ = c * CH, ke_ = c * CH + CH;
            void* args[] = { &Whh_, &xw_, &tb0_, &tb1_, &cb_, &bih_, &bhh_,
                             &h_, &hbf_, &y_, &L_, &kb_, &ke_ };
            hipLaunchCooperativeKernel(reinterpret_cast<void*>(gru_sent_persist),
                                       dim3(44, 4, 2), dim3(128), args, ldsBytes, stream);
        }
    }
    // ---- layer 1: same chunking; input = y0s (K=1400: VEC) ----
    for (int c = 0; c < 2; ++c) {
        int tb0 = c * CH;
        int tb1 = S - c * CH - CH;
        gemm_mfma<bf16, bf16, true><<<dim3((Gs + MBN - 1) / MBN, (CH * B + MBM - 1) / MBM, 2),
                                      256, 0, stream>>>(
            y0s + (long)tb0 * B * (2 * HS), (long)(tb1 - tb0) * B * (2 * HS),
            se_Wih1, (long)Gs * (2 * HS), xw_ch, (long)CH * B * Gs, CH * B, Gs, 2 * HS);
        {
            const bf16* Whh_ = Whh1b; const bf16* xw_ = xw_ch;
            int tb0_ = tb0, tb1_ = tb1, cb_ = CH;
            const float* bih_ = se_bih1; const float* bhh_ = se_bhh1;
            float* h_ = h_s1; bf16* hbf_ = hbf1; bf16* y_ = nullptr;
            int L_ = S, kb_ = c * CH, ke_ = c * CH + CH;
            void* args[] = { &Whh_, &xw_, &tb0_, &tb1_, &cb_, &bih_, &bhh_,
                             &h_, &hbf_, &y_, &L_, &kb_, &ke_ };
            hipLaunchCooperativeKernel(reinterpret_cast<void*>(gru_sent_persist),
                                       dim3(44, 4, 2), dim3(128), args, ldsBytes, stream);
        }
    }

    // out[1, B, 4*HS] = [sf0 | sb0 | sf1 | sb1]  (float32)
    {
        long tot = (long)B * 4 * HS;
        concat4<float><<<(tot + 255) / 256, 256, 0, stream>>>(h_s0, h_s1, (float*)d_out, B, HS);
    }
}

// Round 3
// 6587.718 us; speedup vs baseline: 3.4781x; 3.4781x over previous
//
#include <hip/hip_runtime.h>
#include <hip/hip_bf16.h>

typedef __hip_bfloat16 bf16;
typedef __attribute__((ext_vector_type(8))) short bf16x8;   // MFMA A/B frag (8 bf16)
typedef __attribute__((ext_vector_type(4))) short bf16x4;
typedef __attribute__((ext_vector_type(4))) float f32x4;    // MFMA C/D frag

__device__ __forceinline__ float ldE(const float* p) { return *p; }
__device__ __forceinline__ float ldE(const bf16* p)  { return (float)*p; }
__device__ __forceinline__ void stC(float* p, float v) { *p = v; }
__device__ __forceinline__ void stC(bf16* p, float v)  { *p = __float2bfloat16(v); }

__device__ __forceinline__ short f2s(float f) {
    bf16 b = __float2bfloat16(f);
    return __builtin_bit_cast(short, b);
}

// NaN-proof activations (clamp = no-op on sane data, sanitizes garbage).
__device__ __forceinline__ float sigm(float x) {
    x = fminf(fmaxf(x, -40.f), 40.f);
    return 1.f / (1.f + expf(-x));
}
__device__ __forceinline__ float tanh_s(float x) {
    x = fminf(fmaxf(x, -20.f), 20.f);
    float e = expf(2.f * x);
    return 1.f - 2.f / (e + 1.f);
}

// 16B-aligned 8-element loads -> bf16x8
__device__ __forceinline__ bf16x8 ld8(const bf16* p) {
    return *reinterpret_cast<const bf16x8*>(p);
}
__device__ __forceinline__ bf16x8 ld8(const float* p) {
    const float4 f0 = *reinterpret_cast<const float4*>(p);
    const float4 f1 = *reinterpret_cast<const float4*>(p + 4);
    bf16x8 v;
    v[0] = f2s(f0.x); v[1] = f2s(f0.y); v[2] = f2s(f0.z); v[3] = f2s(f0.w);
    v[4] = f2s(f1.x); v[5] = f2s(f1.y); v[6] = f2s(f1.z); v[7] = f2s(f1.w);
    return v;
}
// 8B-aligned 8-element load (rows with odd*8B stride)
__device__ __forceinline__ bf16x8 ld8_8B(const bf16* p) {
    bf16x4 lo = *reinterpret_cast<const bf16x4*>(p);
    bf16x4 hi = *reinterpret_cast<const bf16x4*>(p + 4);
    bf16x8 v;
    v[0] = lo[0]; v[1] = lo[1]; v[2] = lo[2]; v[3] = lo[3];
    v[4] = hi[0]; v[5] = hi[1]; v[6] = hi[2]; v[7] = hi[3];
    return v;
}

// f32 -> bf16 bulk convert
__global__ void f2b(const float* __restrict__ src, bf16* __restrict__ dst, long n) {
    long i = (long)blockIdx.x * 256 + threadIdx.x;
    if (i < n) dst[i] = __float2bfloat16(src[i]);
}

// ============================ MFMA GEMM ============================
// C[d] = A[d] (MxK row-major) @ W[d]^T (W is NcxK row-major f32, converted to
// bf16 in staging). BM=128 BN=64 BK=32, 256 thr = 4 waves.
#define MBM 128
#define MBN 64
#define MLD 40   // padded LDS row stride in bf16 (80B)

template <typename AT, typename CT, bool VEC>
__global__ __launch_bounds__(256) void gemm_mfma(
    const AT* __restrict__ A, long sAd,
    const float* __restrict__ W, long sWd,
    CT* __restrict__ C, long sCd,
    int M, int Nc, int K)
{
    __shared__ bf16 As[MBM * MLD];
    __shared__ bf16 Ws[MBN * MLD];
    const int d = blockIdx.z;
    A += (long)d * sAd; W += (long)d * sWd; C += (long)d * sCd;
    const int m0 = blockIdx.y * MBM;
    const int n0 = blockIdx.x * MBN;
    const int tid = threadIdx.x;
    const int w = tid >> 6, l = tid & 63;
    const int lr = l & 15, lq = l >> 4;

    f32x4 acc[2][4] = {};

    for (int k0 = 0; k0 < K; k0 += 32) {
        if (VEC) {
#pragma unroll
            for (int i = 0; i < 2; ++i) {
                int u = tid + i * 256;
                int r = u >> 2, kk = (u & 3) * 8;
                bf16x8 v = {};
                if (m0 + r < M && k0 + kk < K)       // K%8==0: in -> all 8 in
                    v = ld8(A + (long)(m0 + r) * K + k0 + kk);
                *reinterpret_cast<bf16x8*>(&As[r * MLD + kk]) = v;
            }
            {
                int r = tid >> 2, kk = (tid & 3) * 8;
                bf16x8 v = {};
                if (n0 + r < Nc && k0 + kk < K)
                    v = ld8(W + (long)(n0 + r) * K + k0 + kk);
                *reinterpret_cast<bf16x8*>(&Ws[r * MLD + kk]) = v;
            }
        } else {
#pragma unroll
            for (int i = 0; i < 8; ++i) {
                int u = tid + i * 256;
                int r = u >> 4, kk = (u & 15) * 2;
                float v0 = 0.f, v1 = 0.f;
                if (m0 + r < M) {
                    const AT* p = A + (long)(m0 + r) * K + k0 + kk;
                    if (k0 + kk < K)     v0 = ldE(p);
                    if (k0 + kk + 1 < K) v1 = ldE(p + 1);
                }
                As[r * MLD + kk]     = __float2bfloat16(v0);
                As[r * MLD + kk + 1] = __float2bfloat16(v1);
            }
#pragma unroll
            for (int i = 0; i < 4; ++i) {
                int u = tid + i * 256;
                int r = u >> 4, kk = (u & 15) * 2;
                float v0 = 0.f, v1 = 0.f;
                if (n0 + r < Nc) {
                    const float* p = W + (long)(n0 + r) * K + k0 + kk;
                    if (k0 + kk < K)     v0 = *p;
                    if (k0 + kk + 1 < K) v1 = *(p + 1);
                }
                Ws[r * MLD + kk]     = __float2bfloat16(v0);
                Ws[r * MLD + kk + 1] = __float2bfloat16(v1);
            }
        }
        __syncthreads();
        bf16x8 af[2], bw[4];
        af[0] = *reinterpret_cast<const bf16x8*>(&As[(w * 32 + lr) * MLD + lq * 8]);
        af[1] = *reinterpret_cast<const bf16x8*>(&As[(w * 32 + 16 + lr) * MLD + lq * 8]);
#pragma unroll
        for (int ni = 0; ni < 4; ++ni)
            bw[ni] = *reinterpret_cast<const bf16x8*>(&Ws[(ni * 16 + lr) * MLD + lq * 8]);
#pragma unroll
        for (int mi = 0; mi < 2; ++mi)
#pragma unroll
            for (int ni = 0; ni < 4; ++ni)
                acc[mi][ni] = __builtin_amdgcn_mfma_f32_16x16x32_bf16(
                    af[mi], bw[ni], acc[mi][ni], 0, 0, 0);
        __syncthreads();
    }
    // D layout: col = lane&15, row = (lane>>4)*4 + reg
#pragma unroll
    for (int mi = 0; mi < 2; ++mi) {
#pragma unroll
        for (int reg = 0; reg < 4; ++reg) {
            int m = m0 + w * 32 + mi * 16 + lq * 4 + reg;
            if (m >= M) continue;
#pragma unroll
            for (int ni = 0; ni < 4; ++ni) {
                int n = n0 + ni * 16 + lr;
                if (n < Nc) stC(&C[(long)m * Nc + n], acc[mi][ni][reg]);
            }
        }
    }
}

// ================== fused sentence GRU step (MFMA, LDS-staged) ==================
// One kernel per time step. Grid (44 j-tiles, 4 m-tiles of 32, 2 dirs) = 352
// blocks x 128 thr (2 waves); wave w owns batch rows mt*32 + w*16 + [0,16).
// Per launch: (a) all 22 A-frags (h_bf rows) issued up front from L2,
// (b) xw gates prefetched (h-independent), (c) the block's Whh slice
// (3 gates x 22 k-steps x 64 lanes x 8 bf16 = 67.6 KB) staged to LDS in exact
// MFMA B-fragment order by all 128 threads in parallel (33 x 16B independent
// loads/thread -> one L2 latency, not 22 serial hops), then 66 conflict-free
// ds_read_b128 + 66 MFMA, fused gate epilogue. h_bf ping-pong across launches.
#define NKS 22                  // ceil(700/32)
#define HBPE (2 * 128 * 700)    // h_bf ping stride in elems

__global__ __launch_bounds__(128) void gru_step_sent(
    const bf16* __restrict__ hr,     // read ping  [2,128,700]
    bf16* __restrict__ hw,           // write pong [2,128,700]
    const bf16* __restrict__ Whh,    // [2,2100,700] bf16
    const bf16* __restrict__ xw,     // [2,Cbuf,128,2100] bf16
    int tb0, int tb1, int Cbuf,
    const float* __restrict__ bih,   // [2,2100]
    const float* __restrict__ bhh,   // [2,2100]
    float* __restrict__ h,           // [2,128,700] f32 master
    bf16* __restrict__ y,            // [L,128,1400] or nullptr
    int L, int step)
{
    extern __shared__ bf16 Wlds[];  // [NKS][3][64][8] = 67,584 B
    const int jt = blockIdx.x, mt = blockIdx.y, d = blockIdx.z;
    const int tid = threadIdx.x;
    const int w = tid >> 6, l = tid & 63;
    const int lr = l & 15, lq = l >> 4;
    const int j0 = jt * 16;
    const int jcol = j0 + lr;
    const bool jok = jcol < 700;

    // ---- (a) all A-frags up front (recurrence-critical path) ----
    const int arow = mt * 32 + w * 16 + lr;              // batch row (<128)
    const bf16* Ab = hr + ((long)d * 128 + arow) * 700;
    bf16x8 areg[NKS];
#pragma unroll
    for (int kk = 0; kk < NKS; ++kk) {
        const int kb = kk * 32 + lq * 8;
        if (kb + 8 <= 700) {
            areg[kk] = ld8_8B(Ab + kb);
        } else {                                  // kb = 696: 4 valid elems
            bf16x8 v = {};
            bf16x4 lo = *reinterpret_cast<const bf16x4*>(Ab + kb);
            v[0] = lo[0]; v[1] = lo[1]; v[2] = lo[2]; v[3] = lo[3];
            areg[kk] = v;
        }
    }

    // ---- (b) xw gates + biases (h-independent) ----
    const int t_eff = (d == 0) ? step : (L - 1 - step);
    const int tl = t_eff - ((d == 0) ? tb0 : tb1);
    const bf16* xbase = xw + ((long)d * Cbuf + tl) * 128 * 2100;
    bf16 xg[3][4];
#pragma unroll
    for (int reg = 0; reg < 4; ++reg) {
        const int m = mt * 32 + w * 16 + lq * 4 + reg;
        const bf16* xp = xbase + (long)m * 2100 + jcol;
#pragma unroll
        for (int g = 0; g < 3; ++g) xg[g][reg] = jok ? xp[g * 700] : bf16(0.f);
    }
    const int jc = jok ? jcol : 699;             // clamp: no OOB bias reads
    const float bir = bih[d * 2100 + jc];
    const float biz = bih[d * 2100 + 700 + jc];
    const float bin = bih[d * 2100 + 1400 + jc];
    const float bhr = bhh[d * 2100 + jc];
    const float bhz = bhh[d * 2100 + 700 + jc];
    const float bhn = bhh[d * 2100 + 1400 + jc];

    // ---- (c) stage Whh fragments to LDS ----
    // unit u = (kk*3+g)*64 + lane ; global row = g*700 + j0 + (lane&15),
    // k = kk*32 + (lane>>4)*8. Zero-pad rows>=700 and k>=700.
    const bf16* Wd = Whh + (long)d * 2100 * 700;
    for (int u = tid; u < NKS * 3 * 64; u += 128) {
        int lane = u & 63;
        int g = (u >> 6) % 3;
        int kk = u / (3 * 64);
        int row = j0 + (lane & 15);
        int k = kk * 32 + (lane >> 4) * 8;
        bf16x8 v = {};
        if (row < 700) {
            const bf16* p = Wd + (long)(g * 700 + row) * 700 + k;
            if (k + 8 <= 700) {
                v = ld8_8B(p);
            } else {
#pragma unroll
                for (int i = 0; i < 8; ++i)
                    if (k + i < 700) v[i] = __builtin_bit_cast(short, p[i]);
            }
        }
        *reinterpret_cast<bf16x8*>(&Wlds[u * 8]) = v;
    }
    __syncthreads();

    // ---- MFMA: 66 ds_read_b128 + 66 mfma ----
    f32x4 acc[3] = {};
#pragma unroll
    for (int kk = 0; kk < NKS; ++kk) {
#pragma unroll
        for (int g = 0; g < 3; ++g) {
            bf16x8 b = *reinterpret_cast<const bf16x8*>(
                &Wlds[((kk * 3 + g) * 64 + l) * 8]);
            acc[g] = __builtin_amdgcn_mfma_f32_16x16x32_bf16(
                areg[kk], b, acc[g], 0, 0, 0);
        }
    }

    // ---- fused gate epilogue ----
    if (jok) {
#pragma unroll
        for (int reg = 0; reg < 4; ++reg) {
            const int m = mt * 32 + w * 16 + lq * 4 + reg;   // D row = batch
            float r  = sigm((float)xg[0][reg] + bir + acc[0][reg] + bhr);
            float z  = sigm((float)xg[1][reg] + biz + acc[1][reg] + bhz);
            float nn = tanh_s((float)xg[2][reg] + bin + r * (acc[2][reg] + bhn));
            const long hidx = ((long)d * 128 + m) * 700 + jcol;
            const float hnew = (1.f - z) * nn + z * h[hidx];
            h[hidx] = hnew;
            hw[hidx] = __float2bfloat16(hnew);
            if (y) y[((long)t_eff * 128 + m) * 1400 + (long)d * 700 + jcol] =
                       __float2bfloat16(hnew);
        }
    }
}

// Word layer-0 GRU step: input gates gathered from embW[tok] (= emb @ Wih0^T).
__global__ void gru_step_word0(
    const int* __restrict__ x,      // [S,T,B]
    const bf16* __restrict__ embW,  // [2, V, 3H]
    const float* __restrict__ gh,   // [2, N, 3H]
    const float* __restrict__ bih,
    const float* __restrict__ bhh,
    float* __restrict__ h,          // [2, N, H]
    bf16* __restrict__ y,           // [T, N, 2H]
    int S, int T, int B, int V, int H, int k)
{
    const int N = S * B;
    long idx = (long)blockIdx.x * 256 + threadIdx.x;
    if (idx >= 2ll * N * H) return;
    int j = idx % H;
    int n = (idx / H) % N;
    int d = idx / ((long)N * H);
    int G = 3 * H;
    int t_eff = (d == 0) ? k : (T - 1 - k);
    int s = n / B, b = n % B;
    int tok = x[((long)s * T + t_eff) * B + b];
    tok = max(0, min(V - 1, tok));

    const bf16*  xp = embW + ((long)d * V + tok) * G;
    const float* gp = gh + ((long)d * N + n) * G;
    const float* bi = bih + (long)d * G;
    const float* bh = bhh + (long)d * G;

    float xr = (float)xp[j]         + bi[j];
    float xz = (float)xp[H + j]     + bi[H + j];
    float xn = (float)xp[2 * H + j] + bi[2 * H + j];
    float hr = gp[j]         + bh[j];
    float hz = gp[H + j]     + bh[H + j];
    float hn = gp[2 * H + j] + bh[2 * H + j];

    float r = sigm(xr + hr);
    float z = sigm(xz + hz);
    float nn = tanh_s(xn + r * hn);

    long hidx = ((long)d * N + n) * H + j;
    float hnew = (1.f - z) * nn + z * h[hidx];
    h[hidx] = hnew;
    y[((long)t_eff * N + n) * (2 * H) + (long)d * H + j] = __float2bfloat16(hnew);
}

// Generic GRU step (word layer 1). xw layout [2, Cbuf, N, 3H].
__global__ void gru_step1(
    const bf16* __restrict__ xw,
    int tb0, int tb1, int Cbuf,
    const float* __restrict__ gh,
    const float* __restrict__ bih,
    const float* __restrict__ bhh,
    float* __restrict__ h,
    bf16* __restrict__ y,
    int N, int H, int L, int k)
{
    long idx = (long)blockIdx.x * 256 + threadIdx.x;
    if (idx >= 2ll * N * H) return;
    int j = idx % H;
    int n = (idx / H) % N;
    int d = idx / ((long)N * H);
    int G = 3 * H;
    int t_eff = (d == 0) ? k : (L - 1 - k);
    int t_local = t_eff - ((d == 0) ? tb0 : tb1);

    const bf16*  xp = xw + (((long)d * Cbuf + t_local) * N + n) * G;
    const float* gp = gh + ((long)d * N + n) * G;
    const float* bi = bih + (long)d * G;
    const float* bh = bhh + (long)d * G;

    float xr = (float)xp[j]         + bi[j];
    float xz = (float)xp[H + j]     + bi[H + j];
    float xn = (float)xp[2 * H + j] + bi[2 * H + j];
    float hr = gp[j]         + bh[j];
    float hz = gp[H + j]     + bh[H + j];
    float hn = gp[2 * H + j] + bh[2 * H + j];

    float r = sigm(xr + hr);
    float z = sigm(xz + hz);
    float nn = tanh_s(xn + r * hn);

    long hidx = ((long)d * N + n) * H + j;
    float hnew = (1.f - z) * nn + z * h[hidx];
    h[hidx] = hnew;
    if (y) y[((long)t_eff * N + n) * (2 * H) + (long)d * H + j] = __float2bfloat16(hnew);
}

// out[n, 4H] = [ha_d0 | ha_d1 | hb_d0 | hb_d1]
template <typename OT>
__global__ void concat4(const float* __restrict__ ha, const float* __restrict__ hb,
                        OT* __restrict__ out, int N, int H)
{
    long idx = (long)blockIdx.x * 256 + threadIdx.x;
    int C4 = 4 * H;
    if (idx >= (long)N * C4) return;
    int c = idx % C4;
    long n = idx / C4;
    int blk = c / H, j = c % H;
    const float* src = (blk < 2) ? ha : hb;
    int dd = blk & 1;
    stC(&out[idx], src[((long)dd * N + n) * H + j]);
}

extern "C" void kernel_launch(void* const* d_in, const int* in_sizes, int n_in,
                              void* d_out, int out_size, void* d_ws, size_t ws_size,
                              hipStream_t stream)
{
    const int S = 120, T = 10, B = 128, E = 80, HW = 75, HS = 700, V = 30000;
    const int Nw = S * B;            // 15360
    const int Gw = 3 * HW;           // 225
    const int Gs = 3 * HS;           // 2100
    const int CH = 60;               // sentence chunk size
    (void)in_sizes; (void)n_in; (void)out_size; (void)ws_size;

    const int*   x       = (const int*)d_in[0];
    const float* emb     = (const float*)d_in[1];
    const float* we_Wih0 = (const float*)d_in[2],  *we_Whh0 = (const float*)d_in[3];
    const float* we_bih0 = (const float*)d_in[4],  *we_bhh0 = (const float*)d_in[5];
    const float* we_Wih1 = (const float*)d_in[6],  *we_Whh1 = (const float*)d_in[7];
    const float* we_bih1 = (const float*)d_in[8],  *we_bhh1 = (const float*)d_in[9];
    const float* se_Wih0 = (const float*)d_in[10], *se_Whh0 = (const float*)d_in[11];
    const float* se_bih0 = (const float*)d_in[12], *se_bhh0 = (const float*)d_in[13];
    const float* se_Wih1 = (const float*)d_in[14], *se_Whh1 = (const float*)d_in[15];
    const float* se_bih1 = (const float*)d_in[16], *se_bhh1 = (const float*)d_in[17];

    // ---- arenas (142.2 MB total; proven-safe < 149 MB) ----
    char* ws = (char*)d_ws;
    const size_t szA = 9216000;    // words bf16 [Nw,300]
    const size_t szB = 46080000;   // y0w bf16 [T*Nw,150] -> y0s bf16 [S*B,1400]=43.0MB
    const size_t szCDE = 68472000; // word: embW 27.0 | gh_w 27.648 | xw_w1 13.824
                                   // sent: xw_chunk bf16 [2,CH,B,Gs] = 64.512MB
    const size_t szF = 9216000;    // h_w0 -> Whh0_bf 5.88 | hbf0 pings 0.7168
    const size_t szG = 9216000;    // h_w1 -> h_s0|h_s1 1.4336 | Whh1_bf 5.88 | hbf1 0.7168
    char* pA = ws;
    char* pB = pA + szA;
    char* pC = pB + szB;
    char* pF = pC + szCDE;
    char* pG = pF + szF;
    const size_t total = szA + szB + szCDE + szF + szG;  // 142,200,000

    bf16*  words  = (bf16*)pA;
    bf16*  y0w    = (bf16*)pB;
    bf16*  y0s    = (bf16*)pB;
    bf16*  embW   = (bf16*)pC;                       // word phase
    float* gh_w   = (float*)(pC + 27000000);
    bf16*  xw_w1  = (bf16*)(pC + 27000000 + 27648000);
    bf16*  xw_ch  = (bf16*)pC;                       // sentence phase (overlays)
    float* h_w0   = (float*)pF;
    float* h_w1   = (float*)pG;
    // sentence-phase overlays (word buffers dead after concat4)
    bf16*  Whh0b  = (bf16*)pF;                       // [2,2100,700] bf16 = 5,880,000B
    bf16*  hbf0   = (bf16*)(pF + 5880000);           // 2 pings x 358,400B
    float* h_s0   = (float*)pG;                      // 716,800B
    float* h_s1   = (float*)(pG + 716800);           // 716,800B
    bf16*  Whh1b  = (bf16*)(pG + 1433600);           // 5,880,000B
    bf16*  hbf1   = (bf16*)(pG + 7313600);           // 716,800B

    hipMemsetAsync(ws, 0, total, stream);  // poison kill + h0 = 0

    // ===================== word encoder =====================
    // embW[d] = emb @ Wih0[d]^T : [V,80] @ [225,80]^T -> [2,V,225]  (K=80: VEC)
    gemm_mfma<float, bf16, true><<<dim3((Gw + MBN - 1) / MBN, (V + MBM - 1) / MBM, 2),
                                   256, 0, stream>>>(
        emb, 0, we_Wih0, (long)Gw * E, embW, (long)V * Gw, V, Gw, E);
    // ---- layer 0 ----
    for (int k = 0; k < T; ++k) {
        gemm_mfma<float, float, false><<<dim3((Gw + MBN - 1) / MBN, (Nw + MBM - 1) / MBM, 2),
                                         256, 0, stream>>>(
            h_w0, (long)Nw * HW, we_Whh0, (long)Gw * HW, gh_w, (long)Nw * Gw, Nw, Gw, HW);
        long tot = 2ll * Nw * HW;
        gru_step_word0<<<(tot + 255) / 256, 256, 0, stream>>>(
            x, embW, gh_w, we_bih0, we_bhh0, h_w0, y0w, S, T, B, V, HW, k);
    }
    // ---- layer 1 ----
    for (int k = 0; k < T; ++k) {
        gemm_mfma<bf16, bf16, false><<<dim3((Gw + MBN - 1) / MBN, (Nw + MBM - 1) / MBM, 2),
                                       256, 0, stream>>>(
            y0w + (long)k * Nw * 2 * HW, (long)(T - 1 - 2 * k) * Nw * 2 * HW,
            we_Wih1, (long)Gw * (2 * HW), xw_w1, (long)Nw * Gw, Nw, Gw, 2 * HW);
        gemm_mfma<float, float, false><<<dim3((Gw + MBN - 1) / MBN, (Nw + MBM - 1) / MBM, 2),
                                         256, 0, stream>>>(
            h_w1, (long)Nw * HW, we_Whh1, (long)Gw * HW, gh_w, (long)Nw * Gw, Nw, Gw, HW);
        long tot = 2ll * Nw * HW;
        gru_step1<<<(tot + 255) / 256, 256, 0, stream>>>(
            xw_w1, k, T - 1 - k, 1, gh_w, we_bih1, we_bhh1, h_w1, nullptr, Nw, HW, T, k);
    }
    {
        long tot = (long)Nw * 4 * HW;
        concat4<bf16><<<(tot + 255) / 256, 256, 0, stream>>>(h_w0, h_w1, words, Nw, HW);
    }

    // ===================== sentence encoder =====================
    // Whh -> bf16 (once); zero recurrent states (regions overlay word h's).
    {
        long nwh = 2LL * Gs * HS;  // 2,940,000
        f2b<<<(nwh + 255) / 256, 256, 0, stream>>>(se_Whh0, Whh0b, nwh);
        f2b<<<(nwh + 255) / 256, 256, 0, stream>>>(se_Whh1, Whh1b, nwh);
    }
    hipMemsetAsync(h_s0, 0, 2 * 716800, stream);   // h_s0 + h_s1
    hipMemsetAsync(hbf0, 0, 716800, stream);       // both pings
    hipMemsetAsync(hbf1, 0, 716800, stream);

    dim3 sgrid(44, 4, 2);   // 16-col j-tiles x 32-row m-tiles x dirs = 352 blocks
    const unsigned ldsBytes = (unsigned)(NKS * 3 * 64 * 8 * sizeof(bf16)); // 67,584

    // ---- layer 0: 2 chunks of 60 steps; xw batched per chunk (K=300) ----
    for (int c = 0; c < 2; ++c) {
        int tb0 = c * CH;               // fwd t-range  [tb0, tb0+CH)
        int tb1 = S - c * CH - CH;      // bwd t-range  [tb1, tb1+CH)
        gemm_mfma<bf16, bf16, false><<<dim3((Gs + MBN - 1) / MBN, (CH * B + MBM - 1) / MBM, 2),
                                       256, 0, stream>>>(
            words + (long)tb0 * B * (4 * HW), (long)(tb1 - tb0) * B * (4 * HW),
            se_Wih0, (long)Gs * (4 * HW), xw_ch, (long)CH * B * Gs, CH * B, Gs, 4 * HW);
        for (int k = c * CH; k < c * CH + CH; ++k) {
            int p = k & 1;
            gru_step_sent<<<sgrid, 128, ldsBytes, stream>>>(
                hbf0 + (long)p * HBPE, hbf0 + (long)(p ^ 1) * HBPE, Whh0b, xw_ch,
                tb0, tb1, CH, se_bih0, se_bhh0, h_s0, y0s, S, k);
        }
    }
    // ---- layer 1: same chunking; input = y0s (K=1400: VEC) ----
    for (int c = 0; c < 2; ++c) {
        int tb0 = c * CH;
        int tb1 = S - c * CH - CH;
        gemm_mfma<bf16, bf16, true><<<dim3((Gs + MBN - 1) / MBN, (CH * B + MBM - 1) / MBM, 2),
                                      256, 0, stream>>>(
            y0s + (long)tb0 * B * (2 * HS), (long)(tb1 - tb0) * B * (2 * HS),
            se_Wih1, (long)Gs * (2 * HS), xw_ch, (long)CH * B * Gs, CH * B, Gs, 2 * HS);
        for (int k = c * CH; k < c * CH + CH; ++k) {
            int p = k & 1;
            gru_step_sent<<<sgrid, 128, ldsBytes, stream>>>(
                hbf1 + (long)p * HBPE, hbf1 + (long)(p ^ 1) * HBPE, Whh1b, xw_ch,
                tb0, tb1, CH, se_bih1, se_bhh1, h_s1, nullptr, S, k);
        }
    }

    // out[1, B, 4*HS] = [sf0 | sb0 | sf1 | sb1]  (float32)
    {
        long tot = (long)B * 4 * HS;
        concat4<float><<<(tot + 255) / 256, 256, 0, stream>>>(h_s0, h_s1, (float*)d_out, B, HS);
    }
}

// Round 4
// 4730.312 us; speedup vs baseline: 4.8439x; 1.3927x over previous
//
#include <hip/hip_runtime.h>
#include <hip/hip_bf16.h>

typedef __hip_bfloat16 bf16;
typedef __attribute__((ext_vector_type(8))) short bf16x8;   // MFMA A/B frag (8 bf16)
typedef __attribute__((ext_vector_type(4))) short bf16x4;
typedef __attribute__((ext_vector_type(4))) float f32x4;    // MFMA C/D frag

__device__ __forceinline__ float ldE(const float* p) { return *p; }
__device__ __forceinline__ float ldE(const bf16* p)  { return (float)*p; }
__device__ __forceinline__ void stC(float* p, float v) { *p = v; }
__device__ __forceinline__ void stC(bf16* p, float v)  { *p = __float2bfloat16(v); }

__device__ __forceinline__ short f2s(float f) {
    bf16 b = __float2bfloat16(f);
    return __builtin_bit_cast(short, b);
}

// NaN-proof activations (clamp = no-op on sane data, sanitizes garbage).
__device__ __forceinline__ float sigm(float x) {
    x = fminf(fmaxf(x, -40.f), 40.f);
    return 1.f / (1.f + expf(-x));
}
__device__ __forceinline__ float tanh_s(float x) {
    x = fminf(fmaxf(x, -20.f), 20.f);
    float e = expf(2.f * x);
    return 1.f - 2.f / (e + 1.f);
}

// 16B-aligned 8-element loads -> bf16x8
__device__ __forceinline__ bf16x8 ld8(const bf16* p) {
    return *reinterpret_cast<const bf16x8*>(p);
}
__device__ __forceinline__ bf16x8 ld8(const float* p) {
    const float4 f0 = *reinterpret_cast<const float4*>(p);
    const float4 f1 = *reinterpret_cast<const float4*>(p + 4);
    bf16x8 v;
    v[0] = f2s(f0.x); v[1] = f2s(f0.y); v[2] = f2s(f0.z); v[3] = f2s(f0.w);
    v[4] = f2s(f1.x); v[5] = f2s(f1.y); v[6] = f2s(f1.z); v[7] = f2s(f1.w);
    return v;
}
// 8B-aligned 8-element load (rows with odd*8B stride)
__device__ __forceinline__ bf16x8 ld8_8B(const bf16* p) {
    bf16x4 lo = *reinterpret_cast<const bf16x4*>(p);
    bf16x4 hi = *reinterpret_cast<const bf16x4*>(p + 4);
    bf16x8 v;
    v[0] = lo[0]; v[1] = lo[1]; v[2] = lo[2]; v[3] = lo[3];
    v[4] = hi[0]; v[5] = hi[1]; v[6] = hi[2]; v[7] = hi[3];
    return v;
}

// f32 -> bf16 bulk convert
__global__ void f2b(const float* __restrict__ src, bf16* __restrict__ dst, long n) {
    long i = (long)blockIdx.x * 256 + threadIdx.x;
    if (i < n) dst[i] = __float2bfloat16(src[i]);
}

// ============================ MFMA GEMM ============================
// C[d] = A[d] (MxK row-major) @ W[d]^T (W is NcxK row-major f32, converted to
// bf16 in staging). BM=128 BN=64 BK=32, 256 thr = 4 waves.
#define MBM 128
#define MBN 64
#define MLD 40   // padded LDS row stride in bf16 (80B)

template <typename AT, typename CT, bool VEC>
__global__ __launch_bounds__(256) void gemm_mfma(
    const AT* __restrict__ A, long sAd,
    const float* __restrict__ W, long sWd,
    CT* __restrict__ C, long sCd,
    int M, int Nc, int K)
{
    __shared__ bf16 As[MBM * MLD];
    __shared__ bf16 Ws[MBN * MLD];
    const int d = blockIdx.z;
    A += (long)d * sAd; W += (long)d * sWd; C += (long)d * sCd;
    const int m0 = blockIdx.y * MBM;
    const int n0 = blockIdx.x * MBN;
    const int tid = threadIdx.x;
    const int w = tid >> 6, l = tid & 63;
    const int lr = l & 15, lq = l >> 4;

    f32x4 acc[2][4] = {};

    for (int k0 = 0; k0 < K; k0 += 32) {
        if (VEC) {
#pragma unroll
            for (int i = 0; i < 2; ++i) {
                int u = tid + i * 256;
                int r = u >> 2, kk = (u & 3) * 8;
                bf16x8 v = {};
                if (m0 + r < M && k0 + kk < K)       // K%8==0: in -> all 8 in
                    v = ld8(A + (long)(m0 + r) * K + k0 + kk);
                *reinterpret_cast<bf16x8*>(&As[r * MLD + kk]) = v;
            }
            {
                int r = tid >> 2, kk = (tid & 3) * 8;
                bf16x8 v = {};
                if (n0 + r < Nc && k0 + kk < K)
                    v = ld8(W + (long)(n0 + r) * K + k0 + kk);
                *reinterpret_cast<bf16x8*>(&Ws[r * MLD + kk]) = v;
            }
        } else {
#pragma unroll
            for (int i = 0; i < 8; ++i) {
                int u = tid + i * 256;
                int r = u >> 4, kk = (u & 15) * 2;
                float v0 = 0.f, v1 = 0.f;
                if (m0 + r < M) {
                    const AT* p = A + (long)(m0 + r) * K + k0 + kk;
                    if (k0 + kk < K)     v0 = ldE(p);
                    if (k0 + kk + 1 < K) v1 = ldE(p + 1);
                }
                As[r * MLD + kk]     = __float2bfloat16(v0);
                As[r * MLD + kk + 1] = __float2bfloat16(v1);
            }
#pragma unroll
            for (int i = 0; i < 4; ++i) {
                int u = tid + i * 256;
                int r = u >> 4, kk = (u & 15) * 2;
                float v0 = 0.f, v1 = 0.f;
                if (n0 + r < Nc) {
                    const float* p = W + (long)(n0 + r) * K + k0 + kk;
                    if (k0 + kk < K)     v0 = *p;
                    if (k0 + kk + 1 < K) v1 = *(p + 1);
                }
                Ws[r * MLD + kk]     = __float2bfloat16(v0);
                Ws[r * MLD + kk + 1] = __float2bfloat16(v1);
            }
        }
        __syncthreads();
        bf16x8 af[2], bw[4];
        af[0] = *reinterpret_cast<const bf16x8*>(&As[(w * 32 + lr) * MLD + lq * 8]);
        af[1] = *reinterpret_cast<const bf16x8*>(&As[(w * 32 + 16 + lr) * MLD + lq * 8]);
#pragma unroll
        for (int ni = 0; ni < 4; ++ni)
            bw[ni] = *reinterpret_cast<const bf16x8*>(&Ws[(ni * 16 + lr) * MLD + lq * 8]);
#pragma unroll
        for (int mi = 0; mi < 2; ++mi)
#pragma unroll
            for (int ni = 0; ni < 4; ++ni)
                acc[mi][ni] = __builtin_amdgcn_mfma_f32_16x16x32_bf16(
                    af[mi], bw[ni], acc[mi][ni], 0, 0, 0);
        __syncthreads();
    }
    // D layout: col = lane&15, row = (lane>>4)*4 + reg
#pragma unroll
    for (int mi = 0; mi < 2; ++mi) {
#pragma unroll
        for (int reg = 0; reg < 4; ++reg) {
            int m = m0 + w * 32 + mi * 16 + lq * 4 + reg;
            if (m >= M) continue;
#pragma unroll
            for (int ni = 0; ni < 4; ++ni) {
                int n = n0 + ni * 16 + lr;
                if (n < Nc) stC(&C[(long)m * Nc + n], acc[mi][ni][reg]);
            }
        }
    }
}

// ========== fused dual-job sentence GRU step (MFMA, LDS-staged) ==========
// Software-pipelined layers: one launch advances up to TWO independent GRU
// recurrences (layer0 chunk c, layer1 chunk c-1) one time step each.
// Grid (44 j-tiles, njobs, 2 dirs); 512 thr = 8 waves; wave w owns batch rows
// w*16+[0,16) (all 128 rows in one block -> Whh staged ONCE per j-tile, 4x
// less L3 traffic than the 4x m-tile split). Per launch: A-frags (h_bf) and
// xw gates issued up front, Whh slice (67.6 KB) staged to LDS in MFMA
// fragment order, 66 conflict-free ds_read_b128 + 66 MFMA per wave, fused
// gate epilogue. h_bf ping-pong across launches.
#define NKS 22                  // ceil(700/32)
#define HBPE (2 * 128 * 700)    // h_bf ping stride in elems

struct StepJob {
    const bf16* Whh;   // [2,2100,700] bf16
    const bf16* xw;    // [2,Cbuf,128,2100] bf16 (chunk-local)
    const float* bih;  // [2,2100]
    const float* bhh;  // [2,2100]
    float* h;          // [2,128,700] f32 master
    const bf16* hr;    // read ping
    bf16* hw;          // write pong
    bf16* y;           // [L,128,1400] or nullptr
    int te0, te1;      // t_eff for d=0 / d=1 (for y writes)
    int tl0, tl1;      // chunk-local t for d=0 / d=1 (for xw reads)
};

__global__ __launch_bounds__(512) void gru_step_sent2(StepJob ja, StepJob jb, int Cbuf)
{
    extern __shared__ bf16 Wlds[];  // [NKS][3][64][8] = 67,584 B
    const StepJob J = blockIdx.y ? jb : ja;
    const int jt = blockIdx.x, d = blockIdx.z;
    const int tid = threadIdx.x;
    const int w = tid >> 6, l = tid & 63;
    const int lr = l & 15, lq = l >> 4;
    const int j0c = jt * 16;
    const int jcol = j0c + lr;
    const bool jok = jcol < 700;

    // ---- (a) all A-frags up front (recurrence-critical path) ----
    const int arow = w * 16 + lr;                    // batch row (<128)
    const bf16* Ab = J.hr + ((long)d * 128 + arow) * 700;
    bf16x8 areg[NKS];
#pragma unroll
    for (int kk = 0; kk < NKS; ++kk) {
        const int kb = kk * 32 + lq * 8;
        if (kb + 8 <= 700) {
            areg[kk] = ld8_8B(Ab + kb);
        } else {                                  // kb = 696: 4 valid elems
            bf16x8 v = {};
            bf16x4 lo = *reinterpret_cast<const bf16x4*>(Ab + kb);
            v[0] = lo[0]; v[1] = lo[1]; v[2] = lo[2]; v[3] = lo[3];
            areg[kk] = v;
        }
    }

    // ---- (b) xw gates + biases (h-independent) ----
    const int te = d ? J.te1 : J.te0;
    const int tl = d ? J.tl1 : J.tl0;
    const bf16* xbase = J.xw + ((long)d * Cbuf + tl) * 128 * 2100;
    bf16 xg[3][4];
#pragma unroll
    for (int reg = 0; reg < 4; ++reg) {
        const int m = w * 16 + lq * 4 + reg;
        const bf16* xp = xbase + (long)m * 2100 + jcol;
#pragma unroll
        for (int g = 0; g < 3; ++g) xg[g][reg] = jok ? xp[g * 700] : bf16(0.f);
    }
    const int jc = jok ? jcol : 699;             // clamp: no OOB bias reads
    const float bir = J.bih[d * 2100 + jc];
    const float biz = J.bih[d * 2100 + 700 + jc];
    const float bin = J.bih[d * 2100 + 1400 + jc];
    const float bhr = J.bhh[d * 2100 + jc];
    const float bhz = J.bhh[d * 2100 + 700 + jc];
    const float bhn = J.bhh[d * 2100 + 1400 + jc];

    // ---- (c) stage Whh fragments to LDS ----
    // unit u = (kk*3+g)*64 + lane ; global row = g*700 + j0c + (lane&15),
    // k = kk*32 + (lane>>4)*8. Zero-pad rows>=700 and k>=700.
    const bf16* Wd = J.Whh + (long)d * 2100 * 700;
    for (int u = tid; u < NKS * 3 * 64; u += 512) {
        int lane = u & 63;
        int g = (u >> 6) % 3;
        int kk = u / (3 * 64);
        int row = j0c + (lane & 15);
        int k = kk * 32 + (lane >> 4) * 8;
        bf16x8 v = {};
        if (row < 700) {
            const bf16* p = Wd + (long)(g * 700 + row) * 700 + k;
            if (k + 8 <= 700) {
                v = ld8_8B(p);
            } else {
#pragma unroll
                for (int i = 0; i < 8; ++i)
                    if (k + i < 700) v[i] = __builtin_bit_cast(short, p[i]);
            }
        }
        *reinterpret_cast<bf16x8*>(&Wlds[u * 8]) = v;
    }
    __syncthreads();

    // ---- MFMA: 66 ds_read_b128 + 66 mfma per wave ----
    f32x4 acc[3] = {};
#pragma unroll
    for (int kk = 0; kk < NKS; ++kk) {
#pragma unroll
        for (int g = 0; g < 3; ++g) {
            bf16x8 b = *reinterpret_cast<const bf16x8*>(
                &Wlds[((kk * 3 + g) * 64 + l) * 8]);
            acc[g] = __builtin_amdgcn_mfma_f32_16x16x32_bf16(
                areg[kk], b, acc[g], 0, 0, 0);
        }
    }

    // ---- fused gate epilogue ----
    if (jok) {
#pragma unroll
        for (int reg = 0; reg < 4; ++reg) {
            const int m = w * 16 + lq * 4 + reg;         // D row = batch
            float r  = sigm((float)xg[0][reg] + bir + acc[0][reg] + bhr);
            float z  = sigm((float)xg[1][reg] + biz + acc[1][reg] + bhz);
            float nn = tanh_s((float)xg[2][reg] + bin + r * (acc[2][reg] + bhn));
            const long hidx = ((long)d * 128 + m) * 700 + jcol;
            const float hnew = (1.f - z) * nn + z * J.h[hidx];
            J.h[hidx] = hnew;
            J.hw[hidx] = __float2bfloat16(hnew);
            if (J.y) J.y[((long)te * 128 + m) * 1400 + (long)d * 700 + jcol] =
                         __float2bfloat16(hnew);
        }
    }
}

// Word layer-0 GRU step: input gates gathered from embW[tok] (= emb @ Wih0^T).
__global__ void gru_step_word0(
    const int* __restrict__ x,      // [S,T,B]
    const bf16* __restrict__ embW,  // [2, V, 3H]
    const float* __restrict__ gh,   // [2, N, 3H]
    const float* __restrict__ bih,
    const float* __restrict__ bhh,
    float* __restrict__ h,          // [2, N, H]
    bf16* __restrict__ y,           // [T, N, 2H]
    int S, int T, int B, int V, int H, int k)
{
    const int N = S * B;
    long idx = (long)blockIdx.x * 256 + threadIdx.x;
    if (idx >= 2ll * N * H) return;
    int j = idx % H;
    int n = (idx / H) % N;
    int d = idx / ((long)N * H);
    int G = 3 * H;
    int t_eff = (d == 0) ? k : (T - 1 - k);
    int s = n / B, b = n % B;
    int tok = x[((long)s * T + t_eff) * B + b];
    tok = max(0, min(V - 1, tok));

    const bf16*  xp = embW + ((long)d * V + tok) * G;
    const float* gp = gh + ((long)d * N + n) * G;
    const float* bi = bih + (long)d * G;
    const float* bh = bhh + (long)d * G;

    float xr = (float)xp[j]         + bi[j];
    float xz = (float)xp[H + j]     + bi[H + j];
    float xn = (float)xp[2 * H + j] + bi[2 * H + j];
    float hr = gp[j]         + bh[j];
    float hz = gp[H + j]     + bh[H + j];
    float hn = gp[2 * H + j] + bh[2 * H + j];

    float r = sigm(xr + hr);
    float z = sigm(xz + hz);
    float nn = tanh_s(xn + r * hn);

    long hidx = ((long)d * N + n) * H + j;
    float hnew = (1.f - z) * nn + z * h[hidx];
    h[hidx] = hnew;
    y[((long)t_eff * N + n) * (2 * H) + (long)d * H + j] = __float2bfloat16(hnew);
}

// Generic GRU step (word layer 1). xw layout [2, Cbuf, N, 3H].
__global__ void gru_step1(
    const bf16* __restrict__ xw,
    int tb0, int tb1, int Cbuf,
    const float* __restrict__ gh,
    const float* __restrict__ bih,
    const float* __restrict__ bhh,
    float* __restrict__ h,
    bf16* __restrict__ y,
    int N, int H, int L, int k)
{
    long idx = (long)blockIdx.x * 256 + threadIdx.x;
    if (idx >= 2ll * N * H) return;
    int j = idx % H;
    int n = (idx / H) % N;
    int d = idx / ((long)N * H);
    int G = 3 * H;
    int t_eff = (d == 0) ? k : (L - 1 - k);
    int t_local = t_eff - ((d == 0) ? tb0 : tb1);

    const bf16*  xp = xw + (((long)d * Cbuf + t_local) * N + n) * G;
    const float* gp = gh + ((long)d * N + n) * G;
    const float* bi = bih + (long)d * G;
    const float* bh = bhh + (long)d * G;

    float xr = (float)xp[j]         + bi[j];
    float xz = (float)xp[H + j]     + bi[H + j];
    float xn = (float)xp[2 * H + j] + bi[2 * H + j];
    float hr = gp[j]         + bh[j];
    float hz = gp[H + j]     + bh[H + j];
    float hn = gp[2 * H + j] + bh[2 * H + j];

    float r = sigm(xr + hr);
    float z = sigm(xz + hz);
    float nn = tanh_s(xn + r * hn);

    long hidx = ((long)d * N + n) * H + j;
    float hnew = (1.f - z) * nn + z * h[hidx];
    h[hidx] = hnew;
    if (y) y[((long)t_eff * N + n) * (2 * H) + (long)d * H + j] = __float2bfloat16(hnew);
}

// out[n, 4H] = [ha_d0 | ha_d1 | hb_d0 | hb_d1]
template <typename OT>
__global__ void concat4(const float* __restrict__ ha, const float* __restrict__ hb,
                        OT* __restrict__ out, int N, int H)
{
    long idx = (long)blockIdx.x * 256 + threadIdx.x;
    int C4 = 4 * H;
    if (idx >= (long)N * C4) return;
    int c = idx % C4;
    long n = idx / C4;
    int blk = c / H, j = c % H;
    const float* src = (blk < 2) ? ha : hb;
    int dd = blk & 1;
    stC(&out[idx], src[((long)dd * N + n) * H + j]);
}

extern "C" void kernel_launch(void* const* d_in, const int* in_sizes, int n_in,
                              void* d_out, int out_size, void* d_ws, size_t ws_size,
                              hipStream_t stream)
{
    const int S = 120, T = 10, B = 128, E = 80, HW = 75, HS = 700, V = 30000;
    const int Nw = S * B;            // 15360
    const int Gw = 3 * HW;           // 225
    const int Gs = 3 * HS;           // 2100
    (void)in_sizes; (void)n_in; (void)out_size; (void)ws_size;

    const int*   x       = (const int*)d_in[0];
    const float* emb     = (const float*)d_in[1];
    const float* we_Wih0 = (const float*)d_in[2],  *we_Whh0 = (const float*)d_in[3];
    const float* we_bih0 = (const float*)d_in[4],  *we_bhh0 = (const float*)d_in[5];
    const float* we_Wih1 = (const float*)d_in[6],  *we_Whh1 = (const float*)d_in[7];
    const float* we_bih1 = (const float*)d_in[8],  *we_bhh1 = (const float*)d_in[9];
    const float* se_Wih0 = (const float*)d_in[10], *se_Whh0 = (const float*)d_in[11];
    const float* se_bih0 = (const float*)d_in[12], *se_bhh0 = (const float*)d_in[13];
    const float* se_Wih1 = (const float*)d_in[14], *se_Whh1 = (const float*)d_in[15];
    const float* se_bih1 = (const float*)d_in[16], *se_bhh1 = (const float*)d_in[17];

    // ---- arenas (142.2 MB total; proven-safe < 149 MB) ----
    char* ws = (char*)d_ws;
    const size_t szA = 9216000;    // words bf16 [Nw,300]
    const size_t szB = 46080000;   // y0w bf16 [T*Nw,150] -> y0s bf16 [S*B,1400]=43.0MB
    const size_t szCDE = 68472000; // word: embW 27.0 | gh_w 27.648 | xw_w1 13.824
                                   // sent: bufL0 32.256 | bufL1 32.256
    const size_t szF = 9216000;    // h_w0 -> Whh0_bf 5.88 | hbf0 pings 1.4336
    const size_t szG = 9216000;    // h_w1 -> h_s0|h_s1 1.4336 | Whh1_bf 5.88 | hbf1 1.4336
    char* pA = ws;
    char* pB = pA + szA;
    char* pC = pB + szB;
    char* pF = pC + szCDE;
    char* pG = pF + szF;
    const size_t total = szA + szB + szCDE + szF + szG;  // 142,200,000

    bf16*  words  = (bf16*)pA;
    bf16*  y0w    = (bf16*)pB;
    bf16*  y0s    = (bf16*)pB;
    bf16*  embW   = (bf16*)pC;                       // word phase
    float* gh_w   = (float*)(pC + 27000000);
    bf16*  xw_w1  = (bf16*)(pC + 27000000 + 27648000);
    float* h_w0   = (float*)pF;
    float* h_w1   = (float*)pG;
    // sentence-phase overlays (word buffers dead after concat4)
    bf16*  bufL0  = (bf16*)pC;                       // [2,30,128,2100]b = 32,256,000
    bf16*  bufL1  = (bf16*)(pC + 32256000);          // 32,256,000
    bf16*  Whh0b  = (bf16*)pF;                       // 5,880,000
    bf16*  hbf0   = (bf16*)(pF + 5880000);           // 2 pings x 358,400
    float* h_s0   = (float*)pG;                      // 716,800
    float* h_s1   = (float*)(pG + 716800);           // 716,800
    bf16*  Whh1b  = (bf16*)(pG + 1433600);           // 5,880,000
    bf16*  hbf1   = (bf16*)(pG + 7313600);           // 716,800

    hipMemsetAsync(ws, 0, total, stream);  // poison kill + h0 = 0

    // ===================== word encoder =====================
    // embW[d] = emb @ Wih0[d]^T : [V,80] @ [225,80]^T -> [2,V,225]  (K=80: VEC)
    gemm_mfma<float, bf16, true><<<dim3((Gw + MBN - 1) / MBN, (V + MBM - 1) / MBM, 2),
                                   256, 0, stream>>>(
        emb, 0, we_Wih0, (long)Gw * E, embW, (long)V * Gw, V, Gw, E);
    // ---- layer 0 ----
    for (int k = 0; k < T; ++k) {
        gemm_mfma<float, float, false><<<dim3((Gw + MBN - 1) / MBN, (Nw + MBM - 1) / MBM, 2),
                                         256, 0, stream>>>(
            h_w0, (long)Nw * HW, we_Whh0, (long)Gw * HW, gh_w, (long)Nw * Gw, Nw, Gw, HW);
        long tot = 2ll * Nw * HW;
        gru_step_word0<<<(tot + 255) / 256, 256, 0, stream>>>(
            x, embW, gh_w, we_bih0, we_bhh0, h_w0, y0w, S, T, B, V, HW, k);
    }
    // ---- layer 1 ----
    for (int k = 0; k < T; ++k) {
        gemm_mfma<bf16, bf16, false><<<dim3((Gw + MBN - 1) / MBN, (Nw + MBM - 1) / MBM, 2),
                                       256, 0, stream>>>(
            y0w + (long)k * Nw * 2 * HW, (long)(T - 1 - 2 * k) * Nw * 2 * HW,
            we_Wih1, (long)Gw * (2 * HW), xw_w1, (long)Nw * Gw, Nw, Gw, 2 * HW);
        gemm_mfma<float, float, false><<<dim3((Gw + MBN - 1) / MBN, (Nw + MBM - 1) / MBM, 2),
                                         256, 0, stream>>>(
            h_w1, (long)Nw * HW, we_Whh1, (long)Gw * HW, gh_w, (long)Nw * Gw, Nw, Gw, HW);
        long tot = 2ll * Nw * HW;
        gru_step1<<<(tot + 255) / 256, 256, 0, stream>>>(
            xw_w1, k, T - 1 - k, 1, gh_w, we_bih1, we_bhh1, h_w1, nullptr, Nw, HW, T, k);
    }
    {
        long tot = (long)Nw * 4 * HW;
        concat4<bf16><<<(tot + 255) / 256, 256, 0, stream>>>(h_w0, h_w1, words, Nw, HW);
    }

    // ===================== sentence encoder =====================
    // Whh -> bf16 (once); zero recurrent states (regions overlay word h's).
    {
        long nwh = 2LL * Gs * HS;  // 2,940,000
        f2b<<<(nwh + 255) / 256, 256, 0, stream>>>(se_Whh0, Whh0b, nwh);
        f2b<<<(nwh + 255) / 256, 256, 0, stream>>>(se_Whh1, Whh1b, nwh);
    }
    hipMemsetAsync(h_s0, 0, 2 * 716800, stream);   // h_s0 + h_s1
    hipMemsetAsync(hbf0, 0, 2 * 716800, stream);   // both pings
    hipMemsetAsync(hbf1, 0, 2 * 716800, stream);

    const unsigned ldsBytes = (unsigned)(NKS * 3 * 64 * 8 * sizeof(bf16)); // 67,584
    const int C2 = 30, NC = 4;   // chunk size / count; pipeline: slot t runs
                                 // layer0 chunk t (t<NC) + layer1 chunk t-1 (t>=1)

    for (int t = 0; t <= NC; ++t) {
        // slot-boundary GEMMs (stream-serialized; single buffer per layer is safe)
        if (t < NC) {               // l0 xw for chunk t (K=300: non-VEC)
            int tb0 = t * C2, tb1 = S - t * C2 - C2;
            gemm_mfma<bf16, bf16, false><<<dim3((Gs + MBN - 1) / MBN,
                                                (C2 * B + MBM - 1) / MBM, 2),
                                           256, 0, stream>>>(
                words + (long)tb0 * B * (4 * HW), (long)(tb1 - tb0) * B * (4 * HW),
                se_Wih0, (long)Gs * (4 * HW), bufL0, (long)C2 * B * Gs, C2 * B, Gs, 4 * HW);
        }
        if (t >= 1) {               // l1 xw for chunk t-1 (K=1400: VEC)
            int c = t - 1, tb0 = c * C2, tb1 = S - c * C2 - C2;
            gemm_mfma<bf16, bf16, true><<<dim3((Gs + MBN - 1) / MBN,
                                               (C2 * B + MBM - 1) / MBM, 2),
                                          256, 0, stream>>>(
                y0s + (long)tb0 * B * (2 * HS), (long)(tb1 - tb0) * B * (2 * HS),
                se_Wih1, (long)Gs * (2 * HS), bufL1, (long)C2 * B * Gs, C2 * B, Gs, 2 * HS);
        }
        // fused step launches
        for (int i = 0; i < C2; ++i) {
            StepJob jobs[2]; int nj = 0;
            if (t < NC) {           // layer-0 job, chunk t
                int k = t * C2 + i;
                StepJob J;
                J.Whh = Whh0b; J.xw = bufL0; J.bih = se_bih0; J.bhh = se_bhh0;
                J.h = h_s0;
                int p = k & 1;
                J.hr = hbf0 + (long)p * HBPE; J.hw = hbf0 + (long)(p ^ 1) * HBPE;
                J.y = y0s;
                J.te0 = k; J.te1 = S - 1 - k; J.tl0 = i; J.tl1 = C2 - 1 - i;
                jobs[nj++] = J;
            }
            if (t >= 1) {           // layer-1 job, chunk t-1
                int k = (t - 1) * C2 + i;
                StepJob J;
                J.Whh = Whh1b; J.xw = bufL1; J.bih = se_bih1; J.bhh = se_bhh1;
                J.h = h_s1;
                int p = k & 1;
                J.hr = hbf1 + (long)p * HBPE; J.hw = hbf1 + (long)(p ^ 1) * HBPE;
                J.y = nullptr;
                J.te0 = k; J.te1 = S - 1 - k; J.tl0 = i; J.tl1 = C2 - 1 - i;
                jobs[nj++] = J;
            }
            if (nj == 1) jobs[1] = jobs[0];
            gru_step_sent2<<<dim3(44, nj, 2), 512, ldsBytes, stream>>>(
                jobs[0], jobs[1], C2);
        }
    }

    // out[1, B, 4*HS] = [sf0 | sb0 | sf1 | sb1]  (float32)
    {
        long tot = (long)B * 4 * HS;
        concat4<float><<<(tot + 255) / 256, 256, 0, stream>>>(h_s0, h_s1, (float*)d_out, B, HS);
    }
}

// Round 5
// 3507.707 us; speedup vs baseline: 6.5322x; 1.3485x over previous
//
#include <hip/hip_runtime.h>
#include <hip/hip_bf16.h>

typedef __hip_bfloat16 bf16;
typedef __attribute__((ext_vector_type(8))) short bf16x8;   // MFMA A/B frag (8 bf16)
typedef __attribute__((ext_vector_type(4))) short bf16x4;
typedef __attribute__((ext_vector_type(4))) float f32x4;    // MFMA C/D frag

__device__ __forceinline__ void stC(float* p, float v) { *p = v; }
__device__ __forceinline__ void stC(bf16* p, float v)  { *p = __float2bfloat16(v); }

__device__ __forceinline__ short f2s(float f) {
    bf16 b = __float2bfloat16(f);
    return __builtin_bit_cast(short, b);
}

// NaN-proof activations (clamp = no-op on sane data, sanitizes garbage).
__device__ __forceinline__ float sigm(float x) {
    x = fminf(fmaxf(x, -40.f), 40.f);
    return 1.f / (1.f + expf(-x));
}
__device__ __forceinline__ float tanh_s(float x) {
    x = fminf(fmaxf(x, -20.f), 20.f);
    float e = expf(2.f * x);
    return 1.f - 2.f / (e + 1.f);
}

// 16B-aligned 8-element loads -> bf16x8
__device__ __forceinline__ bf16x8 ld8(const bf16* p) {
    return *reinterpret_cast<const bf16x8*>(p);
}
__device__ __forceinline__ bf16x8 ld8(const float* p) {
    const float4 f0 = *reinterpret_cast<const float4*>(p);
    const float4 f1 = *reinterpret_cast<const float4*>(p + 4);
    bf16x8 v;
    v[0] = f2s(f0.x); v[1] = f2s(f0.y); v[2] = f2s(f0.z); v[3] = f2s(f0.w);
    v[4] = f2s(f1.x); v[5] = f2s(f1.y); v[6] = f2s(f1.z); v[7] = f2s(f1.w);
    return v;
}
// 8B-aligned 8-element load (rows with odd*8B stride)
__device__ __forceinline__ bf16x8 ld8_8B(const bf16* p) {
    bf16x4 lo = *reinterpret_cast<const bf16x4*>(p);
    bf16x4 hi = *reinterpret_cast<const bf16x4*>(p + 4);
    bf16x8 v;
    v[0] = lo[0]; v[1] = lo[1]; v[2] = lo[2]; v[3] = lo[3];
    v[4] = hi[0]; v[5] = hi[1]; v[6] = hi[2]; v[7] = hi[3];
    return v;
}

// f32 -> bf16 bulk convert
__global__ void f2b(const float* __restrict__ src, bf16* __restrict__ dst, long n) {
    long i = (long)blockIdx.x * 256 + threadIdx.x;
    if (i < n) dst[i] = __float2bfloat16(src[i]);
}
// f32 [rows,Ks] -> bf16 [rows,Kd] with zero pad cols
__global__ void f2bpad(const float* __restrict__ src, bf16* __restrict__ dst,
                       int rows, int Ks, int Kd) {
    long i = (long)blockIdx.x * 256 + threadIdx.x;
    if (i >= (long)rows * Kd) return;
    int c = i % Kd; long r = i / Kd;
    dst[i] = __float2bfloat16(c < Ks ? src[r * Ks + c] : 0.f);
}
// word Wih1 remap: f32 [rows,150] -> bf16 [rows,160]; col c<75 -> c;
// 80<=c<155 -> c-5; else 0 (matches y0w padded layout d*80+j).
__global__ void f2bremap(const float* __restrict__ src, bf16* __restrict__ dst, int rows) {
    long i = (long)blockIdx.x * 256 + threadIdx.x;
    if (i >= (long)rows * 160) return;
    int c = i % 160; long r = i / 160;
    float v = 0.f;
    if (c < 75) v = src[r * 150 + c];
    else if (c >= 80 && c < 155) v = src[r * 150 + c - 5];
    dst[i] = __float2bfloat16(v);
}

// ==================== MFMA GEMM (f32 inputs, embW only) ====================
#define MBM 128
#define MBN 64
#define MLD 40

__global__ __launch_bounds__(256) void gemm_mfma(
    const float* __restrict__ A, long sAd,
    const float* __restrict__ W, long sWd,
    bf16* __restrict__ C, long sCd,
    int M, int Nc, int K)   // K % 8 == 0
{
    __shared__ bf16 As[MBM * MLD];
    __shared__ bf16 Ws[MBN * MLD];
    const int d = blockIdx.z;
    A += (long)d * sAd; W += (long)d * sWd; C += (long)d * sCd;
    const int m0 = blockIdx.y * MBM;
    const int n0 = blockIdx.x * MBN;
    const int tid = threadIdx.x;
    const int w = tid >> 6, l = tid & 63;
    const int lr = l & 15, lq = l >> 4;

    f32x4 acc[2][4] = {};
    for (int k0 = 0; k0 < K; k0 += 32) {
#pragma unroll
        for (int i = 0; i < 2; ++i) {
            int u = tid + i * 256;
            int r = u >> 2, kk = (u & 3) * 8;
            bf16x8 v = {};
            if (m0 + r < M && k0 + kk < K)
                v = ld8(A + (long)(m0 + r) * K + k0 + kk);
            *reinterpret_cast<bf16x8*>(&As[r * MLD + kk]) = v;
        }
        {
            int r = tid >> 2, kk = (tid & 3) * 8;
            bf16x8 v = {};
            if (n0 + r < Nc && k0 + kk < K)
                v = ld8(W + (long)(n0 + r) * K + k0 + kk);
            *reinterpret_cast<bf16x8*>(&Ws[r * MLD + kk]) = v;
        }
        __syncthreads();
        bf16x8 af[2], bw[4];
        af[0] = *reinterpret_cast<const bf16x8*>(&As[(w * 32 + lr) * MLD + lq * 8]);
        af[1] = *reinterpret_cast<const bf16x8*>(&As[(w * 32 + 16 + lr) * MLD + lq * 8]);
#pragma unroll
        for (int ni = 0; ni < 4; ++ni)
            bw[ni] = *reinterpret_cast<const bf16x8*>(&Ws[(ni * 16 + lr) * MLD + lq * 8]);
#pragma unroll
        for (int mi = 0; mi < 2; ++mi)
#pragma unroll
            for (int ni = 0; ni < 4; ++ni)
                acc[mi][ni] = __builtin_amdgcn_mfma_f32_16x16x32_bf16(
                    af[mi], bw[ni], acc[mi][ni], 0, 0, 0);
        __syncthreads();
    }
#pragma unroll
    for (int mi = 0; mi < 2; ++mi)
#pragma unroll
        for (int reg = 0; reg < 4; ++reg) {
            int m = m0 + w * 32 + mi * 16 + lq * 4 + reg;
            if (m >= M) continue;
#pragma unroll
            for (int ni = 0; ni < 4; ++ni) {
                int n = n0 + ni * 16 + lr;
                if (n < Nc) stC(&C[(long)m * Nc + n], acc[mi][ni][reg]);
            }
        }
}

// ============== all-bf16 GEMM, 128x128 tile, band swizzle ==============
// C[d] = A[d] (MxKP bf16, rows 16B-aligned, M%128==0) @ W[d]^T
// (W: [NcPad x KP] bf16, rows >= Nc zero, pad cols zero). Band-of-4 x-tile
// swizzle: 4 consecutive blocks share one A-panel; W panels stay L2-resident.
#define BT_LD 40
__global__ __launch_bounds__(256) void gemm_bt(
    const bf16* __restrict__ A, long sAd,
    const bf16* __restrict__ W, long sWd,
    bf16* __restrict__ C, long sCd,
    int M, int Nc, int KP)
{
    __shared__ bf16 As[128 * BT_LD];
    __shared__ bf16 Ws[128 * BT_LD];
    const int d = blockIdx.z;
    A += (long)d * sAd; W += (long)d * sWd; C += (long)d * sCd;
    const int nx = (Nc + 127) >> 7, ny = M >> 7;
    int id = blockIdx.x;
    int band = id / (4 * ny);
    int rr = id - band * 4 * ny;
    int bw = nx - band * 4; if (bw > 4) bw = 4;
    int bx, by;
    if (bw == 4) { bx = (band << 2) + (rr & 3); by = rr >> 2; }
    else         { bx = (band << 2) + rr % bw;  by = rr / bw; }
    const int m0 = by << 7;
    const int n0 = bx << 7;
    const int tid = threadIdx.x;
    const int w = tid >> 6, l = tid & 63;
    const int lr = l & 15, lq = l >> 4;

    f32x4 acc[2][8] = {};
    const int nks = (KP + 31) >> 5;
    for (int ks = 0; ks < nks; ++ks) {
        const int k0 = ks << 5;
#pragma unroll
        for (int i = 0; i < 2; ++i) {
            int u = tid + (i << 8);
            int r = u >> 2, kk = (u & 3) << 3;
            bf16x8 v = {};
            if (k0 + kk < KP) v = ld8(A + (long)(m0 + r) * KP + k0 + kk);
            *reinterpret_cast<bf16x8*>(&As[r * BT_LD + kk]) = v;
        }
#pragma unroll
        for (int i = 0; i < 2; ++i) {
            int u = tid + (i << 8);
            int r = u >> 2, kk = (u & 3) << 3;
            bf16x8 v = {};
            if (k0 + kk < KP) v = ld8(W + (long)(n0 + r) * KP + k0 + kk);
            *reinterpret_cast<bf16x8*>(&Ws[r * BT_LD + kk]) = v;
        }
        __syncthreads();
        bf16x8 af[2], bw8[8];
        af[0] = *reinterpret_cast<const bf16x8*>(&As[(w * 32 + lr) * BT_LD + lq * 8]);
        af[1] = *reinterpret_cast<const bf16x8*>(&As[(w * 32 + 16 + lr) * BT_LD + lq * 8]);
#pragma unroll
        for (int ni = 0; ni < 8; ++ni)
            bw8[ni] = *reinterpret_cast<const bf16x8*>(&Ws[(ni * 16 + lr) * BT_LD + lq * 8]);
#pragma unroll
        for (int mi = 0; mi < 2; ++mi)
#pragma unroll
            for (int ni = 0; ni < 8; ++ni)
                acc[mi][ni] = __builtin_amdgcn_mfma_f32_16x16x32_bf16(
                    af[mi], bw8[ni], acc[mi][ni], 0, 0, 0);
        __syncthreads();
    }
#pragma unroll
    for (int mi = 0; mi < 2; ++mi)
#pragma unroll
        for (int reg = 0; reg < 4; ++reg) {
            int m = m0 + w * 32 + mi * 16 + lq * 4 + reg;
#pragma unroll
            for (int ni = 0; ni < 8; ++ni) {
                int n = n0 + ni * 16 + lr;
                if (n < Nc) C[(long)m * Nc + n] = __float2bfloat16(acc[mi][ni][reg]);
            }
        }
}

// ========== fused dual-job sentence GRU step (MFMA, LDS-staged) ==========
#define NKS 22                  // ceil(700/32)
#define HBPE (2 * 128 * 700)    // h_bf ping stride in elems

struct StepJob {
    const bf16* Whh;   // [2,2100,700] bf16
    const bf16* xw;    // [2,Cbuf,128,2100] bf16 (chunk-local)
    const float* bih;  // [2,2100]
    const float* bhh;
    float* h;          // [2,128,700] f32 master
    const bf16* hr;    // read ping
    bf16* hw;          // write pong
    bf16* y;           // [L,128,1408] or nullptr
    int te0, te1;      // t_eff for d=0 / d=1 (y writes)
    int tl0, tl1;      // chunk-local t (xw reads)
};

__global__ __launch_bounds__(512) void gru_step_sent2(StepJob ja, StepJob jb, int Cbuf)
{
    extern __shared__ bf16 Wlds[];  // [NKS][3][64][8] = 67,584 B
    const StepJob J = blockIdx.y ? jb : ja;
    const int jt = blockIdx.x, d = blockIdx.z;
    const int tid = threadIdx.x;
    const int w = tid >> 6, l = tid & 63;
    const int lr = l & 15, lq = l >> 4;
    const int j0c = jt * 16;
    const int jcol = j0c + lr;
    const bool jok = jcol < 700;

    const int arow = w * 16 + lr;
    const bf16* Ab = J.hr + ((long)d * 128 + arow) * 700;
    bf16x8 areg[NKS];
#pragma unroll
    for (int kk = 0; kk < NKS; ++kk) {
        const int kb = kk * 32 + lq * 8;
        if (kb + 8 <= 700) {
            areg[kk] = ld8_8B(Ab + kb);
        } else {
            bf16x8 v = {};
            bf16x4 lo = *reinterpret_cast<const bf16x4*>(Ab + kb);
            v[0] = lo[0]; v[1] = lo[1]; v[2] = lo[2]; v[3] = lo[3];
            areg[kk] = v;
        }
    }

    const int te = d ? J.te1 : J.te0;
    const int tl = d ? J.tl1 : J.tl0;
    const bf16* xbase = J.xw + ((long)d * Cbuf + tl) * 128 * 2100;
    bf16 xg[3][4];
#pragma unroll
    for (int reg = 0; reg < 4; ++reg) {
        const int m = w * 16 + lq * 4 + reg;
        const bf16* xp = xbase + (long)m * 2100 + jcol;
#pragma unroll
        for (int g = 0; g < 3; ++g) xg[g][reg] = jok ? xp[g * 700] : bf16(0.f);
    }
    const int jc = jok ? jcol : 699;
    const float bir = J.bih[d * 2100 + jc];
    const float biz = J.bih[d * 2100 + 700 + jc];
    const float bin = J.bih[d * 2100 + 1400 + jc];
    const float bhr = J.bhh[d * 2100 + jc];
    const float bhz = J.bhh[d * 2100 + 700 + jc];
    const float bhn = J.bhh[d * 2100 + 1400 + jc];

    const bf16* Wd = J.Whh + (long)d * 2100 * 700;
    for (int u = tid; u < NKS * 3 * 64; u += 512) {
        int lane = u & 63;
        int g = (u >> 6) % 3;
        int kk = u / (3 * 64);
        int row = j0c + (lane & 15);
        int k = kk * 32 + (lane >> 4) * 8;
        bf16x8 v = {};
        if (row < 700) {
            const bf16* p = Wd + (long)(g * 700 + row) * 700 + k;
            if (k + 8 <= 700) {
                v = ld8_8B(p);
            } else {
#pragma unroll
                for (int i = 0; i < 8; ++i)
                    if (k + i < 700) v[i] = __builtin_bit_cast(short, p[i]);
            }
        }
        *reinterpret_cast<bf16x8*>(&Wlds[u * 8]) = v;
    }
    __syncthreads();

    f32x4 acc[3] = {};
#pragma unroll
    for (int kk = 0; kk < NKS; ++kk)
#pragma unroll
        for (int g = 0; g < 3; ++g) {
            bf16x8 b = *reinterpret_cast<const bf16x8*>(&Wlds[((kk * 3 + g) * 64 + l) * 8]);
            acc[g] = __builtin_amdgcn_mfma_f32_16x16x32_bf16(areg[kk], b, acc[g], 0, 0, 0);
        }

    if (jok) {
#pragma unroll
        for (int reg = 0; reg < 4; ++reg) {
            const int m = w * 16 + lq * 4 + reg;
            float r  = sigm((float)xg[0][reg] + bir + acc[0][reg] + bhr);
            float z  = sigm((float)xg[1][reg] + biz + acc[1][reg] + bhz);
            float nn = tanh_s((float)xg[2][reg] + bin + r * (acc[2][reg] + bhn));
            const long hidx = ((long)d * 128 + m) * 700 + jcol;
            const float hnew = (1.f - z) * nn + z * J.h[hidx];
            J.h[hidx] = hnew;
            J.hw[hidx] = __float2bfloat16(hnew);
            if (J.y) J.y[((long)te * 128 + m) * 1408 + (long)d * 700 + jcol] =
                         __float2bfloat16(hnew);
        }
    }
}

// ============ fused word GRU steps (same structure, H=75) ============
// grid (5 j-tiles, 120 m-tiles, 2 dirs), 512 thr = 8 waves; wave w owns
// batch rows mt*128 + w*16 + [0,16). h ping [2,Nw,96] bf16 (pads zero).
#define WNW 15360

// layer 0: x-gates gathered from embW[tok]; gh via MFMA (3 ksteps).
__global__ __launch_bounds__(512) void gru_word0_fused(
    const int* __restrict__ x,       // [S,T,B]
    const bf16* __restrict__ embW,   // [2,30000,225]
    const bf16* __restrict__ Whh,    // [2,225,80] zero-padded
    const float* __restrict__ bih,   // [2,225]
    const float* __restrict__ bhh,
    const bf16* __restrict__ hr,     // ping [2,Nw,96]
    bf16* __restrict__ hw,           // pong
    float* __restrict__ h,           // [2,Nw,75] f32
    bf16* __restrict__ y,            // [T,Nw,160]
    int T, int k)
{
    __shared__ bf16 Wl[3 * 3 * 64 * 8];
    const int jt = blockIdx.x, mt = blockIdx.y, d = blockIdx.z;
    const int tid = threadIdx.x;
    const int w = tid >> 6, l = tid & 63;
    const int lr = l & 15, lq = l >> 4;
    const int j0c = jt * 16, jcol = j0c + lr;
    const bool jok = jcol < 75;
    const int t_eff = d ? (T - 1 - k) : k;

    const int na = mt * 128 + w * 16 + lr;
    const bf16* Ab = hr + ((long)d * WNW + na) * 96;
    bf16x8 areg[3];
#pragma unroll
    for (int kk = 0; kk < 3; ++kk) areg[kk] = ld8(Ab + kk * 32 + lq * 8);

    float xg[3][4];
#pragma unroll
    for (int reg = 0; reg < 4; ++reg) {
        const int m = mt * 128 + w * 16 + lq * 4 + reg;
        const int s = m >> 7, b = m & 127;
        int tok = x[(s * T + t_eff) * 128 + b];
        tok = max(0, min(29999, tok));
        const bf16* ep = embW + ((long)d * 30000 + tok) * 225;
#pragma unroll
        for (int g = 0; g < 3; ++g)
            xg[g][reg] = jok ? (float)ep[g * 75 + jcol] : 0.f;
    }
    const int jc = jok ? jcol : 74;
    const float bir = bih[d*225+jc], biz = bih[d*225+75+jc], bin = bih[d*225+150+jc];
    const float bhr = bhh[d*225+jc], bhz = bhh[d*225+75+jc], bhn = bhh[d*225+150+jc];

    const bf16* Wd = Whh + (long)d * 225 * 80;
    for (int u = tid; u < 3 * 3 * 64; u += 512) {
        int lane = u & 63;
        int g = (u >> 6) % 3;
        int kk = u / 192;
        int row = j0c + (lane & 15);
        int kb = kk * 32 + (lane >> 4) * 8;
        bf16x8 v = {};
        if (row < 75 && kb < 80) v = ld8_8B(Wd + (long)(g * 75 + row) * 80 + kb);
        *reinterpret_cast<bf16x8*>(&Wl[u * 8]) = v;
    }
    __syncthreads();

    f32x4 acc[3] = {};
#pragma unroll
    for (int kk = 0; kk < 3; ++kk)
#pragma unroll
        for (int g = 0; g < 3; ++g) {
            bf16x8 b8 = *reinterpret_cast<const bf16x8*>(&Wl[((kk*3+g)*64 + l)*8]);
            acc[g] = __builtin_amdgcn_mfma_f32_16x16x32_bf16(areg[kk], b8, acc[g], 0, 0, 0);
        }

    if (jok) {
#pragma unroll
        for (int reg = 0; reg < 4; ++reg) {
            const int m = mt * 128 + w * 16 + lq * 4 + reg;
            float r  = sigm(xg[0][reg] + bir + acc[0][reg] + bhr);
            float z  = sigm(xg[1][reg] + biz + acc[1][reg] + bhz);
            float nn = tanh_s(xg[2][reg] + bin + r * (acc[2][reg] + bhn));
            const long hif = ((long)d * WNW + m) * 75 + jcol;
            const float hnew = (1.f - z) * nn + z * h[hif];
            h[hif] = hnew;
            hw[((long)d * WNW + m) * 96 + jcol] = __float2bfloat16(hnew);
            y[((long)t_eff * WNW + m) * 160 + d * 80 + jcol] = __float2bfloat16(hnew);
        }
    }
}

// layer 1: xw (y0 @ Wih^T, 5 ksteps) AND gh (3 ksteps) fused via MFMA.
__global__ __launch_bounds__(512) void gru_word1_fused(
    const bf16* __restrict__ y0,     // [T,Nw,160]
    const bf16* __restrict__ Wih,    // [2,225,160] remapped
    const bf16* __restrict__ Whh,    // [2,225,80]
    const float* __restrict__ bih,
    const float* __restrict__ bhh,
    const bf16* __restrict__ hr,
    bf16* __restrict__ hw,
    float* __restrict__ h,           // [2,Nw,75]
    int T, int k)
{
    __shared__ bf16 Wl[8 * 3 * 64 * 8];   // 5 xw + 3 hh ksteps
    const int jt = blockIdx.x, mt = blockIdx.y, d = blockIdx.z;
    const int tid = threadIdx.x;
    const int w = tid >> 6, l = tid & 63;
    const int lr = l & 15, lq = l >> 4;
    const int j0c = jt * 16, jcol = j0c + lr;
    const bool jok = jcol < 75;
    const int t_eff = d ? (T - 1 - k) : k;

    const int na = mt * 128 + w * 16 + lr;
    const bf16* A1 = y0 + ((long)t_eff * WNW + na) * 160;
    bf16x8 a1[5];
#pragma unroll
    for (int kk = 0; kk < 5; ++kk) a1[kk] = ld8(A1 + kk * 32 + lq * 8);
    const bf16* A2 = hr + ((long)d * WNW + na) * 96;
    bf16x8 a2[3];
#pragma unroll
    for (int kk = 0; kk < 3; ++kk) a2[kk] = ld8(A2 + kk * 32 + lq * 8);

    const int jc = jok ? jcol : 74;
    const float bir = bih[d*225+jc], biz = bih[d*225+75+jc], bin = bih[d*225+150+jc];
    const float bhr = bhh[d*225+jc], bhz = bhh[d*225+75+jc], bhn = bhh[d*225+150+jc];

    const bf16* Wx = Wih + (long)d * 225 * 160;
    for (int u = tid; u < 960; u += 512) {       // 5*3*64 units
        int lane = u & 63;
        int g = (u >> 6) % 3;
        int kk = u / 192;
        int row = j0c + (lane & 15);
        int kb = kk * 32 + (lane >> 4) * 8;
        bf16x8 v = {};
        if (row < 75) v = ld8(Wx + (long)(g * 75 + row) * 160 + kb);
        *reinterpret_cast<bf16x8*>(&Wl[u * 8]) = v;
    }
    const bf16* Wd = Whh + (long)d * 225 * 80;
    for (int u = tid; u < 576; u += 512) {       // 3*3*64 units
        int lane = u & 63;
        int g = (u >> 6) % 3;
        int kk = u / 192;
        int row = j0c + (lane & 15);
        int kb = kk * 32 + (lane >> 4) * 8;
        bf16x8 v = {};
        if (row < 75 && kb < 80) v = ld8_8B(Wd + (long)(g * 75 + row) * 80 + kb);
        *reinterpret_cast<bf16x8*>(&Wl[(960 + u) * 8]) = v;
    }
    __syncthreads();

    f32x4 ax[3] = {}, ah[3] = {};
#pragma unroll
    for (int kk = 0; kk < 5; ++kk)
#pragma unroll
        for (int g = 0; g < 3; ++g) {
            bf16x8 b8 = *reinterpret_cast<const bf16x8*>(&Wl[((kk*3+g)*64 + l)*8]);
            ax[g] = __builtin_amdgcn_mfma_f32_16x16x32_bf16(a1[kk], b8, ax[g], 0, 0, 0);
        }
#pragma unroll
    for (int kk = 0; kk < 3; ++kk)
#pragma unroll
        for (int g = 0; g < 3; ++g) {
            bf16x8 b8 = *reinterpret_cast<const bf16x8*>(&Wl[(960 + (kk*3+g)*64 + l)*8]);
            ah[g] = __builtin_amdgcn_mfma_f32_16x16x32_bf16(a2[kk], b8, ah[g], 0, 0, 0);
        }

    if (jok) {
#pragma unroll
        for (int reg = 0; reg < 4; ++reg) {
            const int m = mt * 128 + w * 16 + lq * 4 + reg;
            float r  = sigm(ax[0][reg] + bir + ah[0][reg] + bhr);
            float z  = sigm(ax[1][reg] + biz + ah[1][reg] + bhz);
            float nn = tanh_s(ax[2][reg] + bin + r * (ah[2][reg] + bhn));
            const long hif = ((long)d * WNW + m) * 75 + jcol;
            const float hnew = (1.f - z) * nn + z * h[hif];
            h[hif] = hnew;
            hw[((long)d * WNW + m) * 96 + jcol] = __float2bfloat16(hnew);
        }
    }
}

// out[n*OS + c] = [ha_d0 | ha_d1 | hb_d0 | hb_d1], c in [0,4H)
template <typename OT>
__global__ void concat4(const float* __restrict__ ha, const float* __restrict__ hb,
                        OT* __restrict__ out, int N, int H, int OS)
{
    long idx = (long)blockIdx.x * 256 + threadIdx.x;
    int C4 = 4 * H;
    if (idx >= (long)N * C4) return;
    int c = idx % C4;
    long n = idx / C4;
    int blk = c / H, j = c % H;
    const float* src = (blk < 2) ? ha : hb;
    int dd = blk & 1;
    stC(&out[n * (long)OS + c], src[((long)dd * N + n) * H + j]);
}

extern "C" void kernel_launch(void* const* d_in, const int* in_sizes, int n_in,
                              void* d_out, int out_size, void* d_ws, size_t ws_size,
                              hipStream_t stream)
{
    const int S = 120, T = 10, B = 128, E = 80, HW = 75, HS = 700, V = 30000;
    const int Nw = S * B;            // 15360
    const int Gw = 3 * HW;           // 225
    const int Gs = 3 * HS;           // 2100
    (void)in_sizes; (void)n_in; (void)out_size; (void)ws_size;

    const int*   x       = (const int*)d_in[0];
    const float* emb     = (const float*)d_in[1];
    const float* we_Wih0 = (const float*)d_in[2],  *we_Whh0 = (const float*)d_in[3];
    const float* we_bih0 = (const float*)d_in[4],  *we_bhh0 = (const float*)d_in[5];
    const float* we_Wih1 = (const float*)d_in[6],  *we_Whh1 = (const float*)d_in[7];
    const float* we_bih1 = (const float*)d_in[8],  *we_bhh1 = (const float*)d_in[9];
    const float* se_Wih0 = (const float*)d_in[10], *se_Whh0 = (const float*)d_in[11];
    const float* se_bih0 = (const float*)d_in[12], *se_bhh0 = (const float*)d_in[13];
    const float* se_Wih1 = (const float*)d_in[14], *se_Whh1 = (const float*)d_in[15];
    const float* se_bih1 = (const float*)d_in[16], *se_bhh1 = (const float*)d_in[17];

    // ---- arena (132.0 MB total; proven-safe < 142.2 MB) ----
    char* ws = (char*)d_ws;
    const size_t oP1 = 9340000;                  // words bf16 [Nw,304] = 9,338,880
    const size_t oP2 = oP1 + 49152000;           // y0w [10,Nw,160]b | y0s [Nw,1408]b
    const size_t oP3 = oP2 + 43008000;           // embW 27MB | bufL0+bufL1 43MB
    const size_t total = oP3 + 30516480;         // 132,016,480

    // word-phase pointers
    bf16*  words  = (bf16*)ws;
    bf16*  y0w    = (bf16*)(ws + oP1);
    bf16*  embW   = (bf16*)(ws + oP2);
    float* h_w0   = (float*)(ws + oP3);
    float* h_w1   = (float*)(ws + oP3 + 9216000);
    bf16*  pingW  = (bf16*)(ws + oP3 + 18432000);        // 2 x 5,898,240 B
    bf16*  Whh0bw = (bf16*)(ws + oP3 + 30228480);        // [2,225,80]
    bf16*  Whh1bw = (bf16*)(ws + oP3 + 30300480);
    bf16*  Wih1pw = (bf16*)(ws + oP3 + 30372480);        // [2,225,160]
    const long PWE = 2L * Nw * 96;                       // ping stride elems
    // sentence-phase overlays
    bf16*  y0s    = (bf16*)(ws + oP1);                   // [Nw,1408]
    bf16*  bufL0  = (bf16*)(ws + oP2);                   // [2,20,128,2100]
    bf16*  bufL1  = (bf16*)(ws + oP2 + 21504000);
    bf16*  Whh0b  = (bf16*)(ws + oP3);                   // [2,2100,700]
    bf16*  Whh1b  = (bf16*)(ws + oP3 + 5880000);
    bf16*  hbf0   = (bf16*)(ws + oP3 + 11760000);        // 2 pings x 358,400
    bf16*  hbf1   = (bf16*)(ws + oP3 + 12476800);
    float* h_s0   = (float*)(ws + oP3 + 13193600);
    float* h_s1   = (float*)(ws + oP3 + 13910400);
    bf16*  Wih0p  = (bf16*)(ws + oP3 + 14627200);        // [2,2176,304]
    bf16*  Wih1p  = (bf16*)(ws + oP3 + 17273216);        // [2,2176,1408]

    hipMemsetAsync(ws, 0, total, stream);  // poison kill + zeros everywhere

    // ===================== word encoder =====================
    // embW[d] = emb @ Wih0[d]^T : [V,80] @ [225,80]^T -> [2,V,225]
    gemm_mfma<<<dim3((Gw + MBN - 1) / MBN, (V + MBM - 1) / MBM, 2), 256, 0, stream>>>(
        emb, 0, we_Wih0, (long)Gw * E, embW, (long)V * Gw, V, Gw, E);
    // weight prep (bf16, padded)
    for (int d = 0; d < 2; ++d) {
        f2bpad<<<(225 * 80 + 255) / 256, 256, 0, stream>>>(
            we_Whh0 + (long)d * 225 * 75, Whh0bw + (long)d * 225 * 80, 225, 75, 80);
        f2bpad<<<(225 * 80 + 255) / 256, 256, 0, stream>>>(
            we_Whh1 + (long)d * 225 * 75, Whh1bw + (long)d * 225 * 80, 225, 75, 80);
        f2bremap<<<(225 * 160 + 255) / 256, 256, 0, stream>>>(
            we_Wih1 + (long)d * 225 * 150, Wih1pw + (long)d * 225 * 160, 225);
    }
    dim3 wgrid(5, Nw / 128, 2);
    // ---- layer 0 ----
    for (int k = 0; k < T; ++k) {
        int p = k & 1;
        gru_word0_fused<<<wgrid, 512, 0, stream>>>(
            x, embW, Whh0bw, we_bih0, we_bhh0,
            pingW + (long)p * PWE, pingW + (long)(p ^ 1) * PWE, h_w0, y0w, T, k);
    }
    hipMemsetAsync(pingW, 0, 11796480, stream);    // re-zero both pings for layer 1
    // ---- layer 1 ----
    for (int k = 0; k < T; ++k) {
        int p = k & 1;
        gru_word1_fused<<<wgrid, 512, 0, stream>>>(
            y0w, Wih1pw, Whh1bw, we_bih1, we_bhh1,
            pingW + (long)p * PWE, pingW + (long)(p ^ 1) * PWE, h_w1, T, k);
    }
    {
        long tot = (long)Nw * 4 * HW;
        concat4<bf16><<<(tot + 255) / 256, 256, 0, stream>>>(h_w0, h_w1, words, Nw, HW, 304);
    }

    // ===================== sentence encoder =====================
    {
        long nwh = 2LL * Gs * HS;
        f2b<<<(nwh + 255) / 256, 256, 0, stream>>>(se_Whh0, Whh0b, nwh);
        f2b<<<(nwh + 255) / 256, 256, 0, stream>>>(se_Whh1, Whh1b, nwh);
        for (int d = 0; d < 2; ++d) {
            f2bpad<<<((long)2100 * 304 + 255) / 256, 256, 0, stream>>>(
                se_Wih0 + (long)d * 2100 * 300, Wih0p + (long)d * 2176 * 304, 2100, 300, 304);
            f2bpad<<<((long)2100 * 1408 + 255) / 256, 256, 0, stream>>>(
                se_Wih1 + (long)d * 2100 * 1400, Wih1p + (long)d * 2176 * 1408, 2100, 1400, 1408);
        }
    }
    hipMemsetAsync(ws + oP3 + 11760000, 0, 2867200, stream);  // hbf0,hbf1,h_s0,h_s1

    const unsigned ldsBytes = (unsigned)(NKS * 3 * 64 * 8 * sizeof(bf16)); // 67,584
    const int C2 = 20, NC = 6;   // pipeline: slot t = l0 chunk t + l1 chunk t-1
    const int nblk = ((Gs + 127) / 128) * ((C2 * B) / 128);   // 17*20 = 340

    for (int t = 0; t <= NC; ++t) {
        if (t < NC) {               // l0 xw for chunk t (KP=304)
            int tb0 = t * C2, tb1 = S - t * C2 - C2;
            gemm_bt<<<dim3(nblk, 1, 2), 256, 0, stream>>>(
                words + (long)tb0 * B * 304, (long)(tb1 - tb0) * B * 304,
                Wih0p, (long)2176 * 304,
                bufL0, (long)C2 * B * Gs, C2 * B, Gs, 304);
        }
        if (t >= 1) {               // l1 xw for chunk t-1 (KP=1408)
            int c = t - 1, tb0 = c * C2, tb1 = S - c * C2 - C2;
            gemm_bt<<<dim3(nblk, 1, 2), 256, 0, stream>>>(
                y0s + (long)tb0 * B * 1408, (long)(tb1 - tb0) * B * 1408,
                Wih1p, (long)2176 * 1408,
                bufL1, (long)C2 * B * Gs, C2 * B, Gs, 1408);
        }
        for (int i = 0; i < C2; ++i) {
            StepJob jobs[2]; int nj = 0;
            if (t < NC) {           // layer-0 job, chunk t
                int k = t * C2 + i;
                StepJob J;
                J.Whh = Whh0b; J.xw = bufL0; J.bih = se_bih0; J.bhh = se_bhh0;
                J.h = h_s0;
                int p = k & 1;
                J.hr = hbf0 + (long)p * HBPE; J.hw = hbf0 + (long)(p ^ 1) * HBPE;
                J.y = y0s;
                J.te0 = k; J.te1 = S - 1 - k; J.tl0 = i; J.tl1 = C2 - 1 - i;
                jobs[nj++] = J;
            }
            if (t >= 1) {           // layer-1 job, chunk t-1
                int k = (t - 1) * C2 + i;
                StepJob J;
                J.Whh = Whh1b; J.xw = bufL1; J.bih = se_bih1; J.bhh = se_bhh1;
                J.h = h_s1;
                int p = k & 1;
                J.hr = hbf1 + (long)p * HBPE; J.hw = hbf1 + (long)(p ^ 1) * HBPE;
                J.y = nullptr;
                J.te0 = k; J.te1 = S - 1 - k; J.tl0 = i; J.tl1 = C2 - 1 - i;
                jobs[nj++] = J;
            }
            if (nj == 1) jobs[1] = jobs[0];
            gru_step_sent2<<<dim3(44, nj, 2), 512, ldsBytes, stream>>>(
                jobs[0], jobs[1], C2);
        }
    }

    // out[1, B, 4*HS] = [sf0 | sb0 | sf1 | sb1]  (float32)
    {
        long tot = (long)B * 4 * HS;
        concat4<float><<<(tot + 255) / 256, 256, 0, stream>>>(
            h_s0, h_s1, (float*)d_out, B, HS, 4 * HS);
    }
}

// Round 7
// 3313.049 us; speedup vs baseline: 6.9160x; 1.0588x over previous
//
#include <hip/hip_runtime.h>
#include <hip/hip_bf16.h>

typedef __hip_bfloat16 bf16;
typedef __attribute__((ext_vector_type(8))) short bf16x8;   // MFMA A/B frag (8 bf16)
typedef __attribute__((ext_vector_type(4))) short bf16x4;
typedef __attribute__((ext_vector_type(4))) float f32x4;    // MFMA C/D frag

__device__ __forceinline__ void stC(float* p, float v) { *p = v; }
__device__ __forceinline__ void stC(bf16* p, float v)  { *p = __float2bfloat16(v); }

__device__ __forceinline__ short f2s(float f) {
    bf16 b = __float2bfloat16(f);
    return __builtin_bit_cast(short, b);
}

// NaN-proof activations (clamp = no-op on sane data, sanitizes garbage).
__device__ __forceinline__ float sigm(float x) {
    x = fminf(fmaxf(x, -40.f), 40.f);
    return 1.f / (1.f + expf(-x));
}
__device__ __forceinline__ float tanh_s(float x) {
    x = fminf(fmaxf(x, -20.f), 20.f);
    float e = expf(2.f * x);
    return 1.f - 2.f / (e + 1.f);
}

// 16B-aligned 8-element loads -> bf16x8
__device__ __forceinline__ bf16x8 ld8(const bf16* p) {
    return *reinterpret_cast<const bf16x8*>(p);
}
__device__ __forceinline__ bf16x8 ld8(const float* p) {
    const float4 f0 = *reinterpret_cast<const float4*>(p);
    const float4 f1 = *reinterpret_cast<const float4*>(p + 4);
    bf16x8 v;
    v[0] = f2s(f0.x); v[1] = f2s(f0.y); v[2] = f2s(f0.z); v[3] = f2s(f0.w);
    v[4] = f2s(f1.x); v[5] = f2s(f1.y); v[6] = f2s(f1.z); v[7] = f2s(f1.w);
    return v;
}
// 8B-aligned 8-element load (rows with odd*8B stride)
__device__ __forceinline__ bf16x8 ld8_8B(const bf16* p) {
    bf16x4 lo = *reinterpret_cast<const bf16x4*>(p);
    bf16x4 hi = *reinterpret_cast<const bf16x4*>(p + 4);
    bf16x8 v;
    v[0] = lo[0]; v[1] = lo[1]; v[2] = lo[2]; v[3] = lo[3];
    v[4] = hi[0]; v[5] = hi[1]; v[6] = hi[2]; v[7] = hi[3];
    return v;
}

// f32 -> bf16 bulk convert
__global__ void f2b(const float* __restrict__ src, bf16* __restrict__ dst, long n) {
    long i = (long)blockIdx.x * 256 + threadIdx.x;
    if (i < n) dst[i] = __float2bfloat16(src[i]);
}
// f32 [rows,Ks] -> bf16 [rows,Kd] with zero pad cols
__global__ void f2bpad(const float* __restrict__ src, bf16* __restrict__ dst,
                       int rows, int Ks, int Kd) {
    long i = (long)blockIdx.x * 256 + threadIdx.x;
    if (i >= (long)rows * Kd) return;
    int c = i % Kd; long r = i / Kd;
    dst[i] = __float2bfloat16(c < Ks ? src[r * Ks + c] : 0.f);
}
// word Wih1 remap: f32 [rows,150] -> bf16 [rows,160]; col c<75 -> c;
// 80<=c<155 -> c-5; else 0 (matches y0w padded layout d*80+j).
__global__ void f2bremap(const float* __restrict__ src, bf16* __restrict__ dst, int rows) {
    long i = (long)blockIdx.x * 256 + threadIdx.x;
    if (i >= (long)rows * 160) return;
    int c = i % 160; long r = i / 160;
    float v = 0.f;
    if (c < 75) v = src[r * 150 + c];
    else if (c >= 80 && c < 155) v = src[r * 150 + c - 5];
    dst[i] = __float2bfloat16(v);
}

// ==================== MFMA GEMM (f32 inputs, embW only) ====================
#define MBM 128
#define MBN 64
#define MLD 40

__global__ __launch_bounds__(256) void gemm_mfma(
    const float* __restrict__ A, long sAd,
    const float* __restrict__ W, long sWd,
    bf16* __restrict__ C, long sCd,
    int M, int Nc, int K)   // K % 8 == 0
{
    __shared__ bf16 As[MBM * MLD];
    __shared__ bf16 Ws[MBN * MLD];
    const int d = blockIdx.z;
    A += (long)d * sAd; W += (long)d * sWd; C += (long)d * sCd;
    const int m0 = blockIdx.y * MBM;
    const int n0 = blockIdx.x * MBN;
    const int tid = threadIdx.x;
    const int w = tid >> 6, l = tid & 63;
    const int lr = l & 15, lq = l >> 4;

    f32x4 acc[2][4] = {};
    for (int k0 = 0; k0 < K; k0 += 32) {
#pragma unroll
        for (int i = 0; i < 2; ++i) {
            int u = tid + i * 256;
            int r = u >> 2, kk = (u & 3) * 8;
            bf16x8 v = {};
            if (m0 + r < M && k0 + kk < K)
                v = ld8(A + (long)(m0 + r) * K + k0 + kk);
            *reinterpret_cast<bf16x8*>(&As[r * MLD + kk]) = v;
        }
        {
            int r = tid >> 2, kk = (tid & 3) * 8;
            bf16x8 v = {};
            if (n0 + r < Nc && k0 + kk < K)
                v = ld8(W + (long)(n0 + r) * K + k0 + kk);
            *reinterpret_cast<bf16x8*>(&Ws[r * MLD + kk]) = v;
        }
        __syncthreads();
        bf16x8 af[2], bw[4];
        af[0] = *reinterpret_cast<const bf16x8*>(&As[(w * 32 + lr) * MLD + lq * 8]);
        af[1] = *reinterpret_cast<const bf16x8*>(&As[(w * 32 + 16 + lr) * MLD + lq * 8]);
#pragma unroll
        for (int ni = 0; ni < 4; ++ni)
            bw[ni] = *reinterpret_cast<const bf16x8*>(&Ws[(ni * 16 + lr) * MLD + lq * 8]);
#pragma unroll
        for (int mi = 0; mi < 2; ++mi)
#pragma unroll
            for (int ni = 0; ni < 4; ++ni)
                acc[mi][ni] = __builtin_amdgcn_mfma_f32_16x16x32_bf16(
                    af[mi], bw[ni], acc[mi][ni], 0, 0, 0);
        __syncthreads();
    }
#pragma unroll
    for (int mi = 0; mi < 2; ++mi)
#pragma unroll
        for (int reg = 0; reg < 4; ++reg) {
            int m = m0 + w * 32 + mi * 16 + lq * 4 + reg;
            if (m >= M) continue;
#pragma unroll
            for (int ni = 0; ni < 4; ++ni) {
                int n = n0 + ni * 16 + lr;
                if (n < Nc) stC(&C[(long)m * Nc + n], acc[mi][ni][reg]);
            }
        }
}

// ============== all-bf16 GEMM, 128x128 tile, prefetch, band-8 ==============
// C[d] = A[d] (MxKP bf16, M%128==0, KP%8==0) @ W[d]^T
// (W: [NcPad x KP] bf16, NcPad 128-aligned, pad rows/cols zero).
// 1-deep register prefetch; k-tail chunks (KP%32!=0) zeroed via kin guard
// (ROUND-6 BUG FIX: KP=304 tail wrapped into next row without this guard).
// Band-of-8 x-tile swizzle: 8 consecutive x-tiles share A-panels via L2.
#define BT_LD 40
__global__ __launch_bounds__(256) void gemm_bt(
    const bf16* __restrict__ A, long sAd,
    const bf16* __restrict__ W, long sWd,
    bf16* __restrict__ C, long sCd,
    int M, int Nc, int KP)
{
    __shared__ bf16 As[128 * BT_LD];
    __shared__ bf16 Ws[128 * BT_LD];
    const int d = blockIdx.z;
    A += (long)d * sAd; W += (long)d * sWd; C += (long)d * sCd;
    const int nx = (Nc + 127) >> 7, ny = M >> 7;
    int id = blockIdx.x;
    int band = id / (8 * ny);
    int rr = id - band * 8 * ny;
    int bwd = nx - band * 8; if (bwd > 8) bwd = 8;
    const int bx = band * 8 + rr % bwd;
    const int by = rr / bwd;
    const int m0 = by << 7;
    const int n0 = bx << 7;
    const int tid = threadIdx.x;
    const int w = tid >> 6, l = tid & 63;
    const int lr = l & 15, lq = l >> 4;

    const int ur = tid >> 2, ukk = (tid & 3) << 3;   // staging coords
    const bf16x8 z8 = {};
    bf16x8 ra[2], rb[2];
    auto stage = [&](int k0) {
        const bool kin = (k0 + ukk) < KP;            // 8-chunk fully in (KP%8==0)
#pragma unroll
        for (int i = 0; i < 2; ++i)
            ra[i] = kin ? ld8(A + (long)(m0 + ur + (i << 6)) * KP + k0 + ukk) : z8;
#pragma unroll
        for (int i = 0; i < 2; ++i)
            rb[i] = kin ? ld8(W + (long)(n0 + ur + (i << 6)) * KP + k0 + ukk) : z8;
    };

    f32x4 acc[2][8] = {};
    stage(0);
    for (int k0 = 0; k0 < KP; k0 += 32) {
#pragma unroll
        for (int i = 0; i < 2; ++i) {
            *reinterpret_cast<bf16x8*>(&As[(ur + (i << 6)) * BT_LD + ukk]) = ra[i];
            *reinterpret_cast<bf16x8*>(&Ws[(ur + (i << 6)) * BT_LD + ukk]) = rb[i];
        }
        __syncthreads();
        if (k0 + 32 < KP) stage(k0 + 32);          // prefetch overlaps MFMA
        bf16x8 af[2], bw8[8];
        af[0] = *reinterpret_cast<const bf16x8*>(&As[(w * 32 + lr) * BT_LD + lq * 8]);
        af[1] = *reinterpret_cast<const bf16x8*>(&As[(w * 32 + 16 + lr) * BT_LD + lq * 8]);
#pragma unroll
        for (int ni = 0; ni < 8; ++ni)
            bw8[ni] = *reinterpret_cast<const bf16x8*>(&Ws[(ni * 16 + lr) * BT_LD + lq * 8]);
#pragma unroll
        for (int mi = 0; mi < 2; ++mi)
#pragma unroll
            for (int ni = 0; ni < 8; ++ni)
                acc[mi][ni] = __builtin_amdgcn_mfma_f32_16x16x32_bf16(
                    af[mi], bw8[ni], acc[mi][ni], 0, 0, 0);
        __syncthreads();
    }
#pragma unroll
    for (int mi = 0; mi < 2; ++mi)
#pragma unroll
        for (int reg = 0; reg < 4; ++reg) {
            int m = m0 + w * 32 + mi * 16 + lq * 4 + reg;
#pragma unroll
            for (int ni = 0; ni < 8; ++ni) {
                int n = n0 + ni * 16 + lr;
                if (n < Nc) C[(long)m * Nc + n] = __float2bfloat16(acc[mi][ni][reg]);
            }
        }
}

// ========== fused dual-job sentence GRU step (MFMA, LDS-staged) ==========
#define NKS 22                  // ceil(700/32)
#define HBPE (2 * 128 * 700)    // h_bf ping stride in elems

struct StepJob {
    const bf16* Whh;   // [2,2100,700] bf16
    const bf16* xw;    // [2,Cbuf,128,2100] bf16 (chunk-local)
    const float* bih;  // [2,2100]
    const float* bhh;
    float* h;          // [2,128,700] f32 master
    const bf16* hr;    // read ping
    bf16* hw;          // write pong
    bf16* y;           // [L,128,1408] or nullptr
    int te0, te1;      // t_eff for d=0 / d=1 (y writes)
    int tl0, tl1;      // chunk-local t (xw reads)
};

__global__ __launch_bounds__(512) void gru_step_sent2(StepJob ja, StepJob jb, int Cbuf)
{
    extern __shared__ bf16 Wlds[];  // [NKS][3][64][8] = 67,584 B
    const StepJob J = blockIdx.y ? jb : ja;
    const int jt = blockIdx.x, d = blockIdx.z;
    const int tid = threadIdx.x;
    const int w = tid >> 6, l = tid & 63;
    const int lr = l & 15, lq = l >> 4;
    const int j0c = jt * 16;
    const int jcol = j0c + lr;
    const bool jok = jcol < 700;

    // ---- Whh staging loads FIRST (deepest latency: L3/HBM) into regs ----
    const bf16* Wd = J.Whh + (long)d * 2100 * 700;
    bf16x8 wreg[9];
#pragma unroll
    for (int i = 0; i < 9; ++i) {
        int u = tid + i * 512;
        if (u < NKS * 3 * 64) {
            int lane = u & 63;
            int g = (u >> 6) % 3;
            int kk = u / (3 * 64);
            int row = j0c + (lane & 15);
            int k = kk * 32 + (lane >> 4) * 8;
            bf16x8 v = {};
            if (row < 700) {
                const bf16* p = Wd + (long)(g * 700 + row) * 700 + k;
                if (k + 8 <= 700) {
                    v = ld8_8B(p);
                } else {
#pragma unroll
                    for (int t = 0; t < 8; ++t)
                        if (k + t < 700) v[t] = __builtin_bit_cast(short, p[t]);
                }
            }
            wreg[i] = v;
        }
    }

    // ---- A-frags (L2-resident h state) ----
    const int arow = w * 16 + lr;
    const bf16* Ab = J.hr + ((long)d * 128 + arow) * 700;
    bf16x8 areg[NKS];
#pragma unroll
    for (int kk = 0; kk < NKS; ++kk) {
        const int kb = kk * 32 + lq * 8;
        if (kb + 8 <= 700) {
            areg[kk] = ld8_8B(Ab + kb);
        } else {
            bf16x8 v = {};
            bf16x4 lo = *reinterpret_cast<const bf16x4*>(Ab + kb);
            v[0] = lo[0]; v[1] = lo[1]; v[2] = lo[2]; v[3] = lo[3];
            areg[kk] = v;
        }
    }

    // ---- xw gates + biases (h-independent) ----
    const int te = d ? J.te1 : J.te0;
    const int tl = d ? J.tl1 : J.tl0;
    const bf16* xbase = J.xw + ((long)d * Cbuf + tl) * 128 * 2100;
    bf16 xg[3][4];
#pragma unroll
    for (int reg = 0; reg < 4; ++reg) {
        const int m = w * 16 + lq * 4 + reg;
        const bf16* xp = xbase + (long)m * 2100 + jcol;
#pragma unroll
        for (int g = 0; g < 3; ++g) xg[g][reg] = jok ? xp[g * 700] : bf16(0.f);
    }
    const int jc = jok ? jcol : 699;
    const float bir = J.bih[d * 2100 + jc];
    const float biz = J.bih[d * 2100 + 700 + jc];
    const float bin = J.bih[d * 2100 + 1400 + jc];
    const float bhr = J.bhh[d * 2100 + jc];
    const float bhz = J.bhh[d * 2100 + 700 + jc];
    const float bhn = J.bhh[d * 2100 + 1400 + jc];

    // ---- write staged Whh frags to LDS ----
#pragma unroll
    for (int i = 0; i < 9; ++i) {
        int u = tid + i * 512;
        if (u < NKS * 3 * 64)
            *reinterpret_cast<bf16x8*>(&Wlds[u * 8]) = wreg[i];
    }
    __syncthreads();

    f32x4 acc[3] = {};
#pragma unroll
    for (int kk = 0; kk < NKS; ++kk)
#pragma unroll
        for (int g = 0; g < 3; ++g) {
            bf16x8 b = *reinterpret_cast<const bf16x8*>(&Wlds[((kk * 3 + g) * 64 + l) * 8]);
            acc[g] = __builtin_amdgcn_mfma_f32_16x16x32_bf16(areg[kk], b, acc[g], 0, 0, 0);
        }

    if (jok) {
#pragma unroll
        for (int reg = 0; reg < 4; ++reg) {
            const int m = w * 16 + lq * 4 + reg;
            float r  = sigm((float)xg[0][reg] + bir + acc[0][reg] + bhr);
            float z  = sigm((float)xg[1][reg] + biz + acc[1][reg] + bhz);
            float nn = tanh_s((float)xg[2][reg] + bin + r * (acc[2][reg] + bhn));
            const long hidx = ((long)d * 128 + m) * 700 + jcol;
            const float hnew = (1.f - z) * nn + z * J.h[hidx];
            J.h[hidx] = hnew;
            J.hw[hidx] = __float2bfloat16(hnew);
            if (J.y) J.y[((long)te * 128 + m) * 1408 + (long)d * 700 + jcol] =
                         __float2bfloat16(hnew);
        }
    }
}

// ============ fused word GRU steps (same structure, H=75) ============
#define WNW 15360

// layer 0: x-gates gathered from embW[tok]; gh via MFMA (3 ksteps).
__global__ __launch_bounds__(512) void gru_word0_fused(
    const int* __restrict__ x,       // [S,T,B]
    const bf16* __restrict__ embW,   // [2,30000,225]
    const bf16* __restrict__ Whh,    // [2,225,80] zero-padded
    const float* __restrict__ bih,   // [2,225]
    const float* __restrict__ bhh,
    const bf16* __restrict__ hr,     // ping [2,Nw,96]
    bf16* __restrict__ hw,           // pong
    float* __restrict__ h,           // [2,Nw,75] f32
    bf16* __restrict__ y,            // [T,Nw,160]
    int T, int k)
{
    __shared__ bf16 Wl[3 * 3 * 64 * 8];
    const int jt = blockIdx.x, mt = blockIdx.y, d = blockIdx.z;
    const int tid = threadIdx.x;
    const int w = tid >> 6, l = tid & 63;
    const int lr = l & 15, lq = l >> 4;
    const int j0c = jt * 16, jcol = j0c + lr;
    const bool jok = jcol < 75;
    const int t_eff = d ? (T - 1 - k) : k;

    const int na = mt * 128 + w * 16 + lr;
    const bf16* Ab = hr + ((long)d * WNW + na) * 96;
    bf16x8 areg[3];
#pragma unroll
    for (int kk = 0; kk < 3; ++kk) areg[kk] = ld8(Ab + kk * 32 + lq * 8);

    float xg[3][4];
#pragma unroll
    for (int reg = 0; reg < 4; ++reg) {
        const int m = mt * 128 + w * 16 + lq * 4 + reg;
        const int s = m >> 7, b = m & 127;
        int tok = x[(s * T + t_eff) * 128 + b];
        tok = max(0, min(29999, tok));
        const bf16* ep = embW + ((long)d * 30000 + tok) * 225;
#pragma unroll
        for (int g = 0; g < 3; ++g)
            xg[g][reg] = jok ? (float)ep[g * 75 + jcol] : 0.f;
    }
    const int jc = jok ? jcol : 74;
    const float bir = bih[d*225+jc], biz = bih[d*225+75+jc], bin = bih[d*225+150+jc];
    const float bhr = bhh[d*225+jc], bhz = bhh[d*225+75+jc], bhn = bhh[d*225+150+jc];

    const bf16* Wd = Whh + (long)d * 225 * 80;
    for (int u = tid; u < 3 * 3 * 64; u += 512) {
        int lane = u & 63;
        int g = (u >> 6) % 3;
        int kk = u / 192;
        int row = j0c + (lane & 15);
        int kb = kk * 32 + (lane >> 4) * 8;
        bf16x8 v = {};
        if (row < 75 && kb < 80) v = ld8_8B(Wd + (long)(g * 75 + row) * 80 + kb);
        *reinterpret_cast<bf16x8*>(&Wl[u * 8]) = v;
    }
    __syncthreads();

    f32x4 acc[3] = {};
#pragma unroll
    for (int kk = 0; kk < 3; ++kk)
#pragma unroll
        for (int g = 0; g < 3; ++g) {
            bf16x8 b8 = *reinterpret_cast<const bf16x8*>(&Wl[((kk*3+g)*64 + l)*8]);
            acc[g] = __builtin_amdgcn_mfma_f32_16x16x32_bf16(areg[kk], b8, acc[g], 0, 0, 0);
        }

    if (jok) {
#pragma unroll
        for (int reg = 0; reg < 4; ++reg) {
            const int m = mt * 128 + w * 16 + lq * 4 + reg;
            float r  = sigm(xg[0][reg] + bir + acc[0][reg] + bhr);
            float z  = sigm(xg[1][reg] + biz + acc[1][reg] + bhz);
            float nn = tanh_s(xg[2][reg] + bin + r * (acc[2][reg] + bhn));
            const long hif = ((long)d * WNW + m) * 75 + jcol;
            const float hnew = (1.f - z) * nn + z * h[hif];
            h[hif] = hnew;
            hw[((long)d * WNW + m) * 96 + jcol] = __float2bfloat16(hnew);
            y[((long)t_eff * WNW + m) * 160 + d * 80 + jcol] = __float2bfloat16(hnew);
        }
    }
}

// layer 1: xw (y0 @ Wih^T, 5 ksteps) AND gh (3 ksteps) fused via MFMA.
__global__ __launch_bounds__(512) void gru_word1_fused(
    const bf16* __restrict__ y0,     // [T,Nw,160]
    const bf16* __restrict__ Wih,    // [2,225,160] remapped
    const bf16* __restrict__ Whh,    // [2,225,80]
    const float* __restrict__ bih,
    const float* __restrict__ bhh,
    const bf16* __restrict__ hr,
    bf16* __restrict__ hw,
    float* __restrict__ h,           // [2,Nw,75]
    int T, int k)
{
    __shared__ bf16 Wl[8 * 3 * 64 * 8];   // 5 xw + 3 hh ksteps
    const int jt = blockIdx.x, mt = blockIdx.y, d = blockIdx.z;
    const int tid = threadIdx.x;
    const int w = tid >> 6, l = tid & 63;
    const int lr = l & 15, lq = l >> 4;
    const int j0c = jt * 16, jcol = j0c + lr;
    const bool jok = jcol < 75;
    const int t_eff = d ? (T - 1 - k) : k;

    const int na = mt * 128 + w * 16 + lr;
    const bf16* A1 = y0 + ((long)t_eff * WNW + na) * 160;
    bf16x8 a1[5];
#pragma unroll
    for (int kk = 0; kk < 5; ++kk) a1[kk] = ld8(A1 + kk * 32 + lq * 8);
    const bf16* A2 = hr + ((long)d * WNW + na) * 96;
    bf16x8 a2[3];
#pragma unroll
    for (int kk = 0; kk < 3; ++kk) a2[kk] = ld8(A2 + kk * 32 + lq * 8);

    const int jc = jok ? jcol : 74;
    const float bir = bih[d*225+jc], biz = bih[d*225+75+jc], bin = bih[d*225+150+jc];
    const float bhr = bhh[d*225+jc], bhz = bhh[d*225+75+jc], bhn = bhh[d*225+150+jc];

    const bf16* Wx = Wih + (long)d * 225 * 160;
    for (int u = tid; u < 960; u += 512) {       // 5*3*64 units
        int lane = u & 63;
        int g = (u >> 6) % 3;
        int kk = u / 192;
        int row = j0c + (lane & 15);
        int kb = kk * 32 + (lane >> 4) * 8;
        bf16x8 v = {};
        if (row < 75) v = ld8(Wx + (long)(g * 75 + row) * 160 + kb);
        *reinterpret_cast<bf16x8*>(&Wl[u * 8]) = v;
    }
    const bf16* Wd = Whh + (long)d * 225 * 80;
    for (int u = tid; u < 576; u += 512) {       // 3*3*64 units
        int lane = u & 63;
        int g = (u >> 6) % 3;
        int kk = u / 192;
        int row = j0c + (lane & 15);
        int kb = kk * 32 + (lane >> 4) * 8;
        bf16x8 v = {};
        if (row < 75 && kb < 80) v = ld8_8B(Wd + (long)(g * 75 + row) * 80 + kb);
        *reinterpret_cast<bf16x8*>(&Wl[(960 + u) * 8]) = v;
    }
    __syncthreads();

    f32x4 ax[3] = {}, ah[3] = {};
#pragma unroll
    for (int kk = 0; kk < 5; ++kk)
#pragma unroll
        for (int g = 0; g < 3; ++g) {
            bf16x8 b8 = *reinterpret_cast<const bf16x8*>(&Wl[((kk*3+g)*64 + l)*8]);
            ax[g] = __builtin_amdgcn_mfma_f32_16x16x32_bf16(a1[kk], b8, ax[g], 0, 0, 0);
        }
#pragma unroll
    for (int kk = 0; kk < 3; ++kk)
#pragma unroll
        for (int g = 0; g < 3; ++g) {
            bf16x8 b8 = *reinterpret_cast<const bf16x8*>(&Wl[(960 + (kk*3+g)*64 + l)*8]);
            ah[g] = __builtin_amdgcn_mfma_f32_16x16x32_bf16(a2[kk], b8, ah[g], 0, 0, 0);
        }

    if (jok) {
#pragma unroll
        for (int reg = 0; reg < 4; ++reg) {
            const int m = mt * 128 + w * 16 + lq * 4 + reg;
            float r  = sigm(ax[0][reg] + bir + ah[0][reg] + bhr);
            float z  = sigm(ax[1][reg] + biz + ah[1][reg] + bhz);
            float nn = tanh_s(ax[2][reg] + bin + r * (ah[2][reg] + bhn));
            const long hif = ((long)d * WNW + m) * 75 + jcol;
            const float hnew = (1.f - z) * nn + z * h[hif];
            h[hif] = hnew;
            hw[((long)d * WNW + m) * 96 + jcol] = __float2bfloat16(hnew);
        }
    }
}

// out[n*OS + c] = [ha_d0 | ha_d1 | hb_d0 | hb_d1], c in [0,4H)
template <typename OT>
__global__ void concat4(const float* __restrict__ ha, const float* __restrict__ hb,
                        OT* __restrict__ out, int N, int H, int OS)
{
    long idx = (long)blockIdx.x * 256 + threadIdx.x;
    int C4 = 4 * H;
    if (idx >= (long)N * C4) return;
    int c = idx % C4;
    long n = idx / C4;
    int blk = c / H, j = c % H;
    const float* src = (blk < 2) ? ha : hb;
    int dd = blk & 1;
    stC(&out[n * (long)OS + c], src[((long)dd * N + n) * H + j]);
}

extern "C" void kernel_launch(void* const* d_in, const int* in_sizes, int n_in,
                              void* d_out, int out_size, void* d_ws, size_t ws_size,
                              hipStream_t stream)
{
    const int S = 120, T = 10, B = 128, E = 80, HW = 75, HS = 700, V = 30000;
    const int Nw = S * B;            // 15360
    const int Gw = 3 * HW;           // 225
    const int Gs = 3 * HS;           // 2100
    (void)in_sizes; (void)n_in; (void)out_size; (void)ws_size;

    const int*   x       = (const int*)d_in[0];
    const float* emb     = (const float*)d_in[1];
    const float* we_Wih0 = (const float*)d_in[2],  *we_Whh0 = (const float*)d_in[3];
    const float* we_bih0 = (const float*)d_in[4],  *we_bhh0 = (const float*)d_in[5];
    const float* we_Wih1 = (const float*)d_in[6],  *we_Whh1 = (const float*)d_in[7];
    const float* we_bih1 = (const float*)d_in[8],  *we_bhh1 = (const float*)d_in[9];
    const float* se_Wih0 = (const float*)d_in[10], *se_Whh0 = (const float*)d_in[11];
    const float* se_bih0 = (const float*)d_in[12], *se_bhh0 = (const float*)d_in[13];
    const float* se_Wih1 = (const float*)d_in[14], *se_Whh1 = (const float*)d_in[15];
    const float* se_bih1 = (const float*)d_in[16], *se_bhh1 = (const float*)d_in[17];

    // ---- arena (132.0 MB total; proven-safe < 142.2 MB) ----
    char* ws = (char*)d_ws;
    const size_t oP1 = 9340000;                  // words bf16 [Nw,304] = 9,338,880
    const size_t oP2 = oP1 + 49152000;           // y0w [10,Nw,160]b | y0s [Nw,1408]b
    const size_t oP3 = oP2 + 43008000;           // embW 27MB | bufL0+bufL1 43MB
    const size_t total = oP3 + 30516480;         // 132,016,480

    // word-phase pointers
    bf16*  words  = (bf16*)ws;
    bf16*  y0w    = (bf16*)(ws + oP1);
    bf16*  embW   = (bf16*)(ws + oP2);
    float* h_w0   = (float*)(ws + oP3);
    float* h_w1   = (float*)(ws + oP3 + 9216000);
    bf16*  pingW  = (bf16*)(ws + oP3 + 18432000);        // 2 x 5,898,240 B
    bf16*  Whh0bw = (bf16*)(ws + oP3 + 30228480);        // [2,225,80]
    bf16*  Whh1bw = (bf16*)(ws + oP3 + 30300480);
    bf16*  Wih1pw = (bf16*)(ws + oP3 + 30372480);        // [2,225,160]
    const long PWE = 2L * Nw * 96;                       // ping stride elems
    // sentence-phase overlays
    bf16*  y0s    = (bf16*)(ws + oP1);                   // [Nw,1408]
    bf16*  bufL0  = (bf16*)(ws + oP2);                   // [2,20,128,2100]
    bf16*  bufL1  = (bf16*)(ws + oP2 + 21504000);
    bf16*  Whh0b  = (bf16*)(ws + oP3);                   // [2,2100,700]
    bf16*  Whh1b  = (bf16*)(ws + oP3 + 5880000);
    bf16*  hbf0   = (bf16*)(ws + oP3 + 11760000);        // 2 pings x 358,400
    bf16*  hbf1   = (bf16*)(ws + oP3 + 12476800);
    float* h_s0   = (float*)(ws + oP3 + 13193600);
    float* h_s1   = (float*)(ws + oP3 + 13910400);
    bf16*  Wih0p  = (bf16*)(ws + oP3 + 14627200);        // [2,2176,304]
    bf16*  Wih1p  = (bf16*)(ws + oP3 + 17273216);        // [2,2176,1408]

    // Targeted memsets: embW/bufL region (43MB) is fully written before any
    // read; everything else (pads, h states, weight pad rows) zeroed here.
    hipMemsetAsync(ws, 0, oP2, stream);                  // words pads + y0w/y0s holes
    hipMemsetAsync(ws + oP3, 0, 30516480, stream);       // h_w*, pingW, wts (pad rows)

    // ===================== word encoder =====================
    // embW[d] = emb @ Wih0[d]^T : [V,80] @ [225,80]^T -> [2,V,225]
    gemm_mfma<<<dim3((Gw + MBN - 1) / MBN, (V + MBM - 1) / MBM, 2), 256, 0, stream>>>(
        emb, 0, we_Wih0, (long)Gw * E, embW, (long)V * Gw, V, Gw, E);
    // weight prep (bf16, padded)
    for (int d = 0; d < 2; ++d) {
        f2bpad<<<(225 * 80 + 255) / 256, 256, 0, stream>>>(
            we_Whh0 + (long)d * 225 * 75, Whh0bw + (long)d * 225 * 80, 225, 75, 80);
        f2bpad<<<(225 * 80 + 255) / 256, 256, 0, stream>>>(
            we_Whh1 + (long)d * 225 * 75, Whh1bw + (long)d * 225 * 80, 225, 75, 80);
        f2bremap<<<(225 * 160 + 255) / 256, 256, 0, stream>>>(
            we_Wih1 + (long)d * 225 * 150, Wih1pw + (long)d * 225 * 160, 225);
    }
    dim3 wgrid(5, Nw / 128, 2);
    // ---- layer 0 ----
    for (int k = 0; k < T; ++k) {
        int p = k & 1;
        gru_word0_fused<<<wgrid, 512, 0, stream>>>(
            x, embW, Whh0bw, we_bih0, we_bhh0,
            pingW + (long)p * PWE, pingW + (long)(p ^ 1) * PWE, h_w0, y0w, T, k);
    }
    hipMemsetAsync(pingW, 0, 11796480, stream);    // re-zero both pings for layer 1
    // ---- layer 1 ----
    for (int k = 0; k < T; ++k) {
        int p = k & 1;
        gru_word1_fused<<<wgrid, 512, 0, stream>>>(
            y0w, Wih1pw, Whh1bw, we_bih1, we_bhh1,
            pingW + (long)p * PWE, pingW + (long)(p ^ 1) * PWE, h_w1, T, k);
    }
    {
        long tot = (long)Nw * 4 * HW;
        concat4<bf16><<<(tot + 255) / 256, 256, 0, stream>>>(h_w0, h_w1, words, Nw, HW, 304);
    }

    // ===================== sentence encoder =====================
    {
        long nwh = 2LL * Gs * HS;
        f2b<<<(nwh + 255) / 256, 256, 0, stream>>>(se_Whh0, Whh0b, nwh);
        f2b<<<(nwh + 255) / 256, 256, 0, stream>>>(se_Whh1, Whh1b, nwh);
        for (int d = 0; d < 2; ++d) {
            f2bpad<<<((long)2100 * 304 + 255) / 256, 256, 0, stream>>>(
                se_Wih0 + (long)d * 2100 * 300, Wih0p + (long)d * 2176 * 304, 2100, 300, 304);
            f2bpad<<<((long)2100 * 1408 + 255) / 256, 256, 0, stream>>>(
                se_Wih1 + (long)d * 2100 * 1400, Wih1p + (long)d * 2176 * 1408, 2100, 1400, 1408);
        }
    }
    hipMemsetAsync(ws + oP3 + 11760000, 0, 2867200, stream);  // hbf0,hbf1,h_s0,h_s1

    const unsigned ldsBytes = (unsigned)(NKS * 3 * 64 * 8 * sizeof(bf16)); // 67,584
    const int C2 = 20, NC = 6;   // pipeline: slot t = l0 chunk t + l1 chunk t-1
    const int nblk = ((Gs + 127) / 128) * ((C2 * B) / 128);   // 17*20 = 340

    for (int t = 0; t <= NC; ++t) {
        if (t < NC) {               // l0 xw for chunk t (KP=304)
            int tb0 = t * C2, tb1 = S - t * C2 - C2;
            gemm_bt<<<dim3(nblk, 1, 2), 256, 0, stream>>>(
                words + (long)tb0 * B * 304, (long)(tb1 - tb0) * B * 304,
                Wih0p, (long)2176 * 304,
                bufL0, (long)C2 * B * Gs, C2 * B, Gs, 304);
        }
        if (t >= 1) {               // l1 xw for chunk t-1 (KP=1408)
            int c = t - 1, tb0 = c * C2, tb1 = S - c * C2 - C2;
            gemm_bt<<<dim3(nblk, 1, 2), 256, 0, stream>>>(
                y0s + (long)tb0 * B * 1408, (long)(tb1 - tb0) * B * 1408,
                Wih1p, (long)2176 * 1408,
                bufL1, (long)C2 * B * Gs, C2 * B, Gs, 1408);
        }
        for (int i = 0; i < C2; ++i) {
            StepJob jobs[2]; int nj = 0;
            if (t < NC) {           // layer-0 job, chunk t
                int k = t * C2 + i;
                StepJob J;
                J.Whh = Whh0b; J.xw = bufL0; J.bih = se_bih0; J.bhh = se_bhh0;
                J.h = h_s0;
                int p = k & 1;
                J.hr = hbf0 + (long)p * HBPE; J.hw = hbf0 + (long)(p ^ 1) * HBPE;
                J.y = y0s;
                J.te0 = k; J.te1 = S - 1 - k; J.tl0 = i; J.tl1 = C2 - 1 - i;
                jobs[nj++] = J;
            }
            if (t >= 1) {           // layer-1 job, chunk t-1
                int k = (t - 1) * C2 + i;
                StepJob J;
                J.Whh = Whh1b; J.xw = bufL1; J.bih = se_bih1; J.bhh = se_bhh1;
                J.h = h_s1;
                int p = k & 1;
                J.hr = hbf1 + (long)p * HBPE; J.hw = hbf1 + (long)(p ^ 1) * HBPE;
                J.y = nullptr;
                J.te0 = k; J.te1 = S - 1 - k; J.tl0 = i; J.tl1 = C2 - 1 - i;
                jobs[nj++] = J;
            }
            if (nj == 1) jobs[1] = jobs[0];
            gru_step_sent2<<<dim3(44, nj, 2), 512, ldsBytes, stream>>>(
                jobs[0], jobs[1], C2);
        }
    }

    // out[1, B, 4*HS] = [sf0 | sb0 | sf1 | sb1]  (float32)
    {
        long tot = (long)B * 4 * HS;
        concat4<float><<<(tot + 255) / 256, 256, 0, stream>>>(
            h_s0, h_s1, (float*)d_out, B, HS, 4 * HS);
    }
}

// Round 9
// 3224.222 us; speedup vs baseline: 7.1065x; 1.0275x over previous
//
#include <hip/hip_runtime.h>
#include <hip/hip_bf16.h>

typedef __hip_bfloat16 bf16;
typedef __attribute__((ext_vector_type(8))) short bf16x8;   // MFMA A/B frag (8 bf16)
typedef __attribute__((ext_vector_type(4))) short bf16x4;
typedef __attribute__((ext_vector_type(4))) float f32x4;    // MFMA C/D frag

__device__ __forceinline__ void stC(float* p, float v) { *p = v; }
__device__ __forceinline__ void stC(bf16* p, float v)  { *p = __float2bfloat16(v); }

__device__ __forceinline__ short f2s(float f) {
    bf16 b = __float2bfloat16(f);
    return __builtin_bit_cast(short, b);
}

// NaN-proof activations (clamp = no-op on sane data, sanitizes garbage).
__device__ __forceinline__ float sigm(float x) {
    x = fminf(fmaxf(x, -40.f), 40.f);
    return 1.f / (1.f + expf(-x));
}
__device__ __forceinline__ float tanh_s(float x) {
    x = fminf(fmaxf(x, -20.f), 20.f);
    float e = expf(2.f * x);
    return 1.f - 2.f / (e + 1.f);
}

// 16B-aligned 8-element loads -> bf16x8
__device__ __forceinline__ bf16x8 ld8(const bf16* p) {
    return *reinterpret_cast<const bf16x8*>(p);
}
__device__ __forceinline__ bf16x8 ld8(const float* p) {
    const float4 f0 = *reinterpret_cast<const float4*>(p);
    const float4 f1 = *reinterpret_cast<const float4*>(p + 4);
    bf16x8 v;
    v[0] = f2s(f0.x); v[1] = f2s(f0.y); v[2] = f2s(f0.z); v[3] = f2s(f0.w);
    v[4] = f2s(f1.x); v[5] = f2s(f1.y); v[6] = f2s(f1.z); v[7] = f2s(f1.w);
    return v;
}
// 8B-aligned 8-element load (rows with odd*8B stride)
__device__ __forceinline__ bf16x8 ld8_8B(const bf16* p) {
    bf16x4 lo = *reinterpret_cast<const bf16x4*>(p);
    bf16x4 hi = *reinterpret_cast<const bf16x4*>(p + 4);
    bf16x8 v;
    v[0] = lo[0]; v[1] = lo[1]; v[2] = lo[2]; v[3] = lo[3];
    v[4] = hi[0]; v[5] = hi[1]; v[6] = hi[2]; v[7] = hi[3];
    return v;
}

// f32 -> bf16 bulk convert
__global__ void f2b(const float* __restrict__ src, bf16* __restrict__ dst, long n) {
    long i = (long)blockIdx.x * 256 + threadIdx.x;
    if (i < n) dst[i] = __float2bfloat16(src[i]);
}
// f32 [rows,Ks] -> bf16 [rows,Kd] with zero pad cols
__global__ void f2bpad(const float* __restrict__ src, bf16* __restrict__ dst,
                       int rows, int Ks, int Kd) {
    long i = (long)blockIdx.x * 256 + threadIdx.x;
    if (i >= (long)rows * Kd) return;
    int c = i % Kd; long r = i / Kd;
    dst[i] = __float2bfloat16(c < Ks ? src[r * Ks + c] : 0.f);
}
// word Wih1 remap: f32 [rows,150] -> bf16 [rows,160]; col c<75 -> c;
// 80<=c<155 -> c-5; else 0 (matches y0w padded layout d*80+j).
__global__ void f2bremap(const float* __restrict__ src, bf16* __restrict__ dst, int rows) {
    long i = (long)blockIdx.x * 256 + threadIdx.x;
    if (i >= (long)rows * 160) return;
    int c = i % 160; long r = i / 160;
    float v = 0.f;
    if (c < 75) v = src[r * 150 + c];
    else if (c >= 80 && c < 155) v = src[r * 150 + c - 5];
    dst[i] = __float2bfloat16(v);
}

// ==================== MFMA GEMM (f32 inputs, embW only) ====================
#define MBM 128
#define MBN 64
#define MLD 40

__global__ __launch_bounds__(256) void gemm_mfma(
    const float* __restrict__ A, long sAd,
    const float* __restrict__ W, long sWd,
    bf16* __restrict__ C, long sCd,
    int M, int Nc, int K)   // K % 8 == 0
{
    __shared__ bf16 As[MBM * MLD];
    __shared__ bf16 Ws[MBN * MLD];
    const int d = blockIdx.z;
    A += (long)d * sAd; W += (long)d * sWd; C += (long)d * sCd;
    const int m0 = blockIdx.y * MBM;
    const int n0 = blockIdx.x * MBN;
    const int tid = threadIdx.x;
    const int w = tid >> 6, l = tid & 63;
    const int lr = l & 15, lq = l >> 4;

    f32x4 acc[2][4] = {};
    for (int k0 = 0; k0 < K; k0 += 32) {
#pragma unroll
        for (int i = 0; i < 2; ++i) {
            int u = tid + i * 256;
            int r = u >> 2, kk = (u & 3) * 8;
            bf16x8 v = {};
            if (m0 + r < M && k0 + kk < K)
                v = ld8(A + (long)(m0 + r) * K + k0 + kk);
            *reinterpret_cast<bf16x8*>(&As[r * MLD + kk]) = v;
        }
        {
            int r = tid >> 2, kk = (tid & 3) * 8;
            bf16x8 v = {};
            if (n0 + r < Nc && k0 + kk < K)
                v = ld8(W + (long)(n0 + r) * K + k0 + kk);
            *reinterpret_cast<bf16x8*>(&Ws[r * MLD + kk]) = v;
        }
        __syncthreads();
        bf16x8 af[2], bw[4];
        af[0] = *reinterpret_cast<const bf16x8*>(&As[(w * 32 + lr) * MLD + lq * 8]);
        af[1] = *reinterpret_cast<const bf16x8*>(&As[(w * 32 + 16 + lr) * MLD + lq * 8]);
#pragma unroll
        for (int ni = 0; ni < 4; ++ni)
            bw[ni] = *reinterpret_cast<const bf16x8*>(&Ws[(ni * 16 + lr) * MLD + lq * 8]);
#pragma unroll
        for (int mi = 0; mi < 2; ++mi)
#pragma unroll
            for (int ni = 0; ni < 4; ++ni)
                acc[mi][ni] = __builtin_amdgcn_mfma_f32_16x16x32_bf16(
                    af[mi], bw[ni], acc[mi][ni], 0, 0, 0);
        __syncthreads();
    }
#pragma unroll
    for (int mi = 0; mi < 2; ++mi)
#pragma unroll
        for (int reg = 0; reg < 4; ++reg) {
            int m = m0 + w * 32 + mi * 16 + lq * 4 + reg;
            if (m >= M) continue;
#pragma unroll
            for (int ni = 0; ni < 4; ++ni) {
                int n = n0 + ni * 16 + lr;
                if (n < Nc) stC(&C[(long)m * Nc + n], acc[mi][ni][reg]);
            }
        }
}

// ===== all-bf16 GEMM: 128x128 tile, BK=64, XOR-swizzled LDS, prefetch =====
// C[d] = A[d] (MxKP bf16, M%128==0, KP%8==0) @ W[d]^T
// (W: [NcPad x KP] bf16, NcPad 128-aligned, pad rows/cols zero).
// LDS: linear [128][64] bf16 (128B rows -> bank = 16B-granule only) with
// granule ^= (row&7) on write AND read -> reads/writes at the bank
// throughput floor (round-7 counters: BT_LD=40 padding was ~8-way excess,
// 8.6M conflict cycles). BK=64: 32 MFMAs per barrier. 1-deep register
// prefetch; KP tail (KP%64!=0) zeroed via kin guard. Band-of-8 x-tile
// swizzle for A-panel L2 reuse.
__global__ __launch_bounds__(256) void gemm_bt(
    const bf16* __restrict__ A, long sAd,
    const bf16* __restrict__ W, long sWd,
    bf16* __restrict__ C, long sCd,
    int M, int Nc, int KP)
{
    __shared__ bf16 As[128 * 64];
    __shared__ bf16 Ws[128 * 64];
    const int d = blockIdx.z;
    A += (long)d * sAd; W += (long)d * sWd; C += (long)d * sCd;
    const int nx = (Nc + 127) >> 7, ny = M >> 7;
    int id = blockIdx.x;
    int band = id / (8 * ny);
    int rr = id - band * 8 * ny;
    int bwd = nx - band * 8; if (bwd > 8) bwd = 8;
    const int bx = band * 8 + rr % bwd;
    const int by = rr / bwd;
    const int m0 = by << 7;
    const int n0 = bx << 7;
    const int tid = threadIdx.x;
    const int w = tid >> 6, l = tid & 63;
    const int lr = l & 15, lq = l >> 4;

    const int sr = tid >> 3;            // staging row base 0..31 (+32*i)
    const int sg = tid & 7;             // staging 8-elem granule 0..7
    const bf16x8 z8 = {};
    bf16x8 ra[4], rb[4];
    auto stage = [&](int k0) {
        const bool kin = (k0 + sg * 8) < KP;     // whole granule in (KP%8==0)
#pragma unroll
        for (int i = 0; i < 4; ++i)
            ra[i] = kin ? ld8(A + (long)(m0 + sr + i * 32) * KP + k0 + sg * 8) : z8;
#pragma unroll
        for (int i = 0; i < 4; ++i)
            rb[i] = kin ? ld8(W + (long)(n0 + sr + i * 32) * KP + k0 + sg * 8) : z8;
    };

    f32x4 acc[2][8] = {};
    stage(0);
    for (int k0 = 0; k0 < KP; k0 += 64) {
#pragma unroll
        for (int i = 0; i < 4; ++i) {
            const int r = sr + i * 32;
            const int g = sg ^ (r & 7);          // XOR-granule swizzle (write)
            *reinterpret_cast<bf16x8*>(&As[r * 64 + g * 8]) = ra[i];
            *reinterpret_cast<bf16x8*>(&Ws[r * 64 + g * 8]) = rb[i];
        }
        __syncthreads();
        if (k0 + 64 < KP) stage(k0 + 64);        // prefetch overlaps MFMA
#pragma unroll
        for (int ks = 0; ks < 2; ++ks) {
            const int gb = ks * 4 + lq;          // pre-swizzle granule
            bf16x8 af[2], bw8[8];
#pragma unroll
            for (int mi = 0; mi < 2; ++mi) {
                const int r = w * 32 + mi * 16 + lr;
                af[mi] = *reinterpret_cast<const bf16x8*>(
                    &As[r * 64 + (gb ^ (r & 7)) * 8]);
            }
#pragma unroll
            for (int ni = 0; ni < 8; ++ni) {
                const int r = ni * 16 + lr;
                bw8[ni] = *reinterpret_cast<const bf16x8*>(
                    &Ws[r * 64 + (gb ^ (r & 7)) * 8]);
            }
#pragma unroll
            for (int mi = 0; mi < 2; ++mi)
#pragma unroll
                for (int ni = 0; ni < 8; ++ni)
                    acc[mi][ni] = __builtin_amdgcn_mfma_f32_16x16x32_bf16(
                        af[mi], bw8[ni], acc[mi][ni], 0, 0, 0);
        }
        __syncthreads();
    }
#pragma unroll
    for (int mi = 0; mi < 2; ++mi)
#pragma unroll
        for (int reg = 0; reg < 4; ++reg) {
            int m = m0 + w * 32 + mi * 16 + lq * 4 + reg;
#pragma unroll
            for (int ni = 0; ni < 8; ++ni) {
                int n = n0 + ni * 16 + lr;
                if (n < Nc) C[(long)m * Nc + n] = __float2bfloat16(acc[mi][ni][reg]);
            }
        }
}

// ========== fused dual-job sentence GRU step (MFMA, LDS-staged) ==========
#define NKS 22                  // ceil(700/32)
#define HBPE (2 * 128 * 700)    // h_bf ping stride in elems

struct StepJob {
    const bf16* Whh;   // [2,2100,700] bf16
    const bf16* xw;    // [2,Cbuf,128,2100] bf16 (chunk-local)
    const float* bih;  // [2,2100]
    const float* bhh;
    float* h;          // [2,128,700] f32 master
    const bf16* hr;    // read ping
    bf16* hw;          // write pong
    bf16* y;           // [L,128,1408] or nullptr
    int te0, te1;      // t_eff for d=0 / d=1 (y writes)
    int tl0, tl1;      // chunk-local t (xw reads)
};

__global__ __launch_bounds__(512) void gru_step_sent2(StepJob ja, StepJob jb, int Cbuf)
{
    extern __shared__ bf16 Wlds[];  // [NKS][3][64][8] = 67,584 B
    const StepJob J = blockIdx.y ? jb : ja;
    const int jt = blockIdx.x, d = blockIdx.z;
    const int tid = threadIdx.x;
    const int w = tid >> 6, l = tid & 63;
    const int lr = l & 15, lq = l >> 4;
    const int j0c = jt * 16;
    const int jcol = j0c + lr;
    const bool jok = jcol < 700;

    // ---- Whh staging loads FIRST (deepest latency: L3/HBM) into regs ----
    const bf16* Wd = J.Whh + (long)d * 2100 * 700;
    bf16x8 wreg[9];
#pragma unroll
    for (int i = 0; i < 9; ++i) {
        int u = tid + i * 512;
        if (u < NKS * 3 * 64) {
            int lane = u & 63;
            int g = (u >> 6) % 3;
            int kk = u / (3 * 64);
            int row = j0c + (lane & 15);
            int k = kk * 32 + (lane >> 4) * 8;
            bf16x8 v = {};
            if (row < 700) {
                const bf16* p = Wd + (long)(g * 700 + row) * 700 + k;
                if (k + 8 <= 700) {
                    v = ld8_8B(p);
                } else {
#pragma unroll
                    for (int t = 0; t < 8; ++t)
                        if (k + t < 700) v[t] = __builtin_bit_cast(short, p[t]);
                }
            }
            wreg[i] = v;
        }
    }

    // ---- A-frags (L2-resident h state) ----
    const int arow = w * 16 + lr;
    const bf16* Ab = J.hr + ((long)d * 128 + arow) * 700;
    bf16x8 areg[NKS];
#pragma unroll
    for (int kk = 0; kk < NKS; ++kk) {
        const int kb = kk * 32 + lq * 8;
        if (kb + 8 <= 700) {
            areg[kk] = ld8_8B(Ab + kb);
        } else {
            bf16x8 v = {};
            bf16x4 lo = *reinterpret_cast<const bf16x4*>(Ab + kb);
            v[0] = lo[0]; v[1] = lo[1]; v[2] = lo[2]; v[3] = lo[3];
            areg[kk] = v;
        }
    }

    // ---- xw gates + biases (h-independent) ----
    const int te = d ? J.te1 : J.te0;
    const int tl = d ? J.tl1 : J.tl0;
    const bf16* xbase = J.xw + ((long)d * Cbuf + tl) * 128 * 2100;
    bf16 xg[3][4];
#pragma unroll
    for (int reg = 0; reg < 4; ++reg) {
        const int m = w * 16 + lq * 4 + reg;
        const bf16* xp = xbase + (long)m * 2100 + jcol;
#pragma unroll
        for (int g = 0; g < 3; ++g) xg[g][reg] = jok ? xp[g * 700] : bf16(0.f);
    }
    const int jc = jok ? jcol : 699;
    const float bir = J.bih[d * 2100 + jc];
    const float biz = J.bih[d * 2100 + 700 + jc];
    const float bin = J.bih[d * 2100 + 1400 + jc];
    const float bhr = J.bhh[d * 2100 + jc];
    const float bhz = J.bhh[d * 2100 + 700 + jc];
    const float bhn = J.bhh[d * 2100 + 1400 + jc];

    // ---- write staged Whh frags to LDS ----
#pragma unroll
    for (int i = 0; i < 9; ++i) {
        int u = tid + i * 512;
        if (u < NKS * 3 * 64)
            *reinterpret_cast<bf16x8*>(&Wlds[u * 8]) = wreg[i];
    }
    __syncthreads();

    f32x4 acc[3] = {};
#pragma unroll
    for (int kk = 0; kk < NKS; ++kk)
#pragma unroll
        for (int g = 0; g < 3; ++g) {
            bf16x8 b = *reinterpret_cast<const bf16x8*>(&Wlds[((kk * 3 + g) * 64 + l) * 8]);
            acc[g] = __builtin_amdgcn_mfma_f32_16x16x32_bf16(areg[kk], b, acc[g], 0, 0, 0);
        }

    if (jok) {
#pragma unroll
        for (int reg = 0; reg < 4; ++reg) {
            const int m = w * 16 + lq * 4 + reg;
            float r  = sigm((float)xg[0][reg] + bir + acc[0][reg] + bhr);
            float z  = sigm((float)xg[1][reg] + biz + acc[1][reg] + bhz);
            float nn = tanh_s((float)xg[2][reg] + bin + r * (acc[2][reg] + bhn));
            const long hidx = ((long)d * 128 + m) * 700 + jcol;
            const float hnew = (1.f - z) * nn + z * J.h[hidx];
            J.h[hidx] = hnew;
            J.hw[hidx] = __float2bfloat16(hnew);
            if (J.y) J.y[((long)te * 128 + m) * 1408 + (long)d * 700 + jcol] =
                         __float2bfloat16(hnew);
        }
    }
}

// ============ fused word GRU steps (same structure, H=75) ============
#define WNW 15360

// layer 0: x-gates gathered from embW[tok]; gh via MFMA (3 ksteps).
__global__ __launch_bounds__(512) void gru_word0_fused(
    const int* __restrict__ x,       // [S,T,B]
    const bf16* __restrict__ embW,   // [2,30000,225]
    const bf16* __restrict__ Whh,    // [2,225,80] zero-padded
    const float* __restrict__ bih,   // [2,225]
    const float* __restrict__ bhh,
    const bf16* __restrict__ hr,     // ping [2,Nw,96]
    bf16* __restrict__ hw,           // pong
    float* __restrict__ h,           // [2,Nw,75] f32
    bf16* __restrict__ y,            // [T,Nw,160]
    int T, int k)
{
    __shared__ bf16 Wl[3 * 3 * 64 * 8];
    const int jt = blockIdx.x, mt = blockIdx.y, d = blockIdx.z;
    const int tid = threadIdx.x;
    const int w = tid >> 6, l = tid & 63;
    const int lr = l & 15, lq = l >> 4;
    const int j0c = jt * 16, jcol = j0c + lr;
    const bool jok = jcol < 75;
    const int t_eff = d ? (T - 1 - k) : k;

    const int na = mt * 128 + w * 16 + lr;
    const bf16* Ab = hr + ((long)d * WNW + na) * 96;
    bf16x8 areg[3];
#pragma unroll
    for (int kk = 0; kk < 3; ++kk) areg[kk] = ld8(Ab + kk * 32 + lq * 8);

    float xg[3][4];
#pragma unroll
    for (int reg = 0; reg < 4; ++reg) {
        const int m = mt * 128 + w * 16 + lq * 4 + reg;
        const int s = m >> 7, b = m & 127;
        int tok = x[(s * T + t_eff) * 128 + b];
        tok = max(0, min(29999, tok));
        const bf16* ep = embW + ((long)d * 30000 + tok) * 225;
#pragma unroll
        for (int g = 0; g < 3; ++g)
            xg[g][reg] = jok ? (float)ep[g * 75 + jcol] : 0.f;
    }
    const int jc = jok ? jcol : 74;
    const float bir = bih[d*225+jc], biz = bih[d*225+75+jc], bin = bih[d*225+150+jc];
    const float bhr = bhh[d*225+jc], bhz = bhh[d*225+75+jc], bhn = bhh[d*225+150+jc];

    const bf16* Wd = Whh + (long)d * 225 * 80;
    for (int u = tid; u < 3 * 3 * 64; u += 512) {
        int lane = u & 63;
        int g = (u >> 6) % 3;
        int kk = u / 192;
        int row = j0c + (lane & 15);
        int kb = kk * 32 + (lane >> 4) * 8;
        bf16x8 v = {};
        if (row < 75 && kb < 80) v = ld8_8B(Wd + (long)(g * 75 + row) * 80 + kb);
        *reinterpret_cast<bf16x8*>(&Wl[u * 8]) = v;
    }
    __syncthreads();

    f32x4 acc[3] = {};
#pragma unroll
    for (int kk = 0; kk < 3; ++kk)
#pragma unroll
        for (int g = 0; g < 3; ++g) {
            bf16x8 b8 = *reinterpret_cast<const bf16x8*>(&Wl[((kk*3+g)*64 + l)*8]);
            acc[g] = __builtin_amdgcn_mfma_f32_16x16x32_bf16(areg[kk], b8, acc[g], 0, 0, 0);
        }

    if (jok) {
#pragma unroll
        for (int reg = 0; reg < 4; ++reg) {
            const int m = mt * 128 + w * 16 + lq * 4 + reg;
            float r  = sigm(xg[0][reg] + bir + acc[0][reg] + bhr);
            float z  = sigm(xg[1][reg] + biz + acc[1][reg] + bhz);
            float nn = tanh_s(xg[2][reg] + bin + r * (acc[2][reg] + bhn));
            const long hif = ((long)d * WNW + m) * 75 + jcol;
            const float hnew = (1.f - z) * nn + z * h[hif];
            h[hif] = hnew;
            hw[((long)d * WNW + m) * 96 + jcol] = __float2bfloat16(hnew);
            y[((long)t_eff * WNW + m) * 160 + d * 80 + jcol] = __float2bfloat16(hnew);
        }
    }
}

// layer 1: xw (y0 @ Wih^T, 5 ksteps) AND gh (3 ksteps) fused via MFMA.
__global__ __launch_bounds__(512) void gru_word1_fused(
    const bf16* __restrict__ y0,     // [T,Nw,160]
    const bf16* __restrict__ Wih,    // [2,225,160] remapped
    const bf16* __restrict__ Whh,    // [2,225,80]
    const float* __restrict__ bih,
    const float* __restrict__ bhh,
    const bf16* __restrict__ hr,
    bf16* __restrict__ hw,
    float* __restrict__ h,           // [2,Nw,75]
    int T, int k)
{
    __shared__ bf16 Wl[8 * 3 * 64 * 8];   // 5 xw + 3 hh ksteps
    const int jt = blockIdx.x, mt = blockIdx.y, d = blockIdx.z;
    const int tid = threadIdx.x;
    const int w = tid >> 6, l = tid & 63;
    const int lr = l & 15, lq = l >> 4;
    const int j0c = jt * 16, jcol = j0c + lr;
    const bool jok = jcol < 75;
    const int t_eff = d ? (T - 1 - k) : k;

    const int na = mt * 128 + w * 16 + lr;
    const bf16* A1 = y0 + ((long)t_eff * WNW + na) * 160;
    bf16x8 a1[5];
#pragma unroll
    for (int kk = 0; kk < 5; ++kk) a1[kk] = ld8(A1 + kk * 32 + lq * 8);
    const bf16* A2 = hr + ((long)d * WNW + na) * 96;
    bf16x8 a2[3];
#pragma unroll
    for (int kk = 0; kk < 3; ++kk) a2[kk] = ld8(A2 + kk * 32 + lq * 8);

    const int jc = jok ? jcol : 74;
    const float bir = bih[d*225+jc], biz = bih[d*225+75+jc], bin = bih[d*225+150+jc];
    const float bhr = bhh[d*225+jc], bhz = bhh[d*225+75+jc], bhn = bhh[d*225+150+jc];

    const bf16* Wx = Wih + (long)d * 225 * 160;
    for (int u = tid; u < 960; u += 512) {       // 5*3*64 units
        int lane = u & 63;
        int g = (u >> 6) % 3;
        int kk = u / 192;
        int row = j0c + (lane & 15);
        int kb = kk * 32 + (lane >> 4) * 8;
        bf16x8 v = {};
        if (row < 75) v = ld8(Wx + (long)(g * 75 + row) * 160 + kb);
        *reinterpret_cast<bf16x8*>(&Wl[u * 8]) = v;
    }
    const bf16* Wd = Whh + (long)d * 225 * 80;
    for (int u = tid; u < 576; u += 512) {       // 3*3*64 units
        int lane = u & 63;
        int g = (u >> 6) % 3;
        int kk = u / 192;
        int row = j0c + (lane & 15);
        int kb = kk * 32 + (lane >> 4) * 8;
        bf16x8 v = {};
        if (row < 75 && kb < 80) v = ld8_8B(Wd + (long)(g * 75 + row) * 80 + kb);
        *reinterpret_cast<bf16x8*>(&Wl[(960 + u) * 8]) = v;
    }
    __syncthreads();

    f32x4 ax[3] = {}, ah[3] = {};
#pragma unroll
    for (int kk = 0; kk < 5; ++kk)
#pragma unroll
        for (int g = 0; g < 3; ++g) {
            bf16x8 b8 = *reinterpret_cast<const bf16x8*>(&Wl[((kk*3+g)*64 + l)*8]);
            ax[g] = __builtin_amdgcn_mfma_f32_16x16x32_bf16(a1[kk], b8, ax[g], 0, 0, 0);
        }
#pragma unroll
    for (int kk = 0; kk < 3; ++kk)
#pragma unroll
        for (int g = 0; g < 3; ++g) {
            bf16x8 b8 = *reinterpret_cast<const bf16x8*>(&Wl[(960 + (kk*3+g)*64 + l)*8]);
            ah[g] = __builtin_amdgcn_mfma_f32_16x16x32_bf16(a2[kk], b8, ah[g], 0, 0, 0);
        }

    if (jok) {
#pragma unroll
        for (int reg = 0; reg < 4; ++reg) {
            const int m = mt * 128 + w * 16 + lq * 4 + reg;
            float r  = sigm(ax[0][reg] + bir + ah[0][reg] + bhr);
            float z  = sigm(ax[1][reg] + biz + ah[1][reg] + bhz);
            float nn = tanh_s(ax[2][reg] + bin + r * (ah[2][reg] + bhn));
            const long hif = ((long)d * WNW + m) * 75 + jcol;
            const float hnew = (1.f - z) * nn + z * h[hif];
            h[hif] = hnew;
            hw[((long)d * WNW + m) * 96 + jcol] = __float2bfloat16(hnew);
        }
    }
}

// out[n*OS + c] = [ha_d0 | ha_d1 | hb_d0 | hb_d1], c in [0,4H)
template <typename OT>
__global__ void concat4(const float* __restrict__ ha, const float* __restrict__ hb,
                        OT* __restrict__ out, int N, int H, int OS)
{
    long idx = (long)blockIdx.x * 256 + threadIdx.x;
    int C4 = 4 * H;
    if (idx >= (long)N * C4) return;
    int c = idx % C4;
    long n = idx / C4;
    int blk = c / H, j = c % H;
    const float* src = (blk < 2) ? ha : hb;
    int dd = blk & 1;
    stC(&out[n * (long)OS + c], src[((long)dd * N + n) * H + j]);
}

extern "C" void kernel_launch(void* const* d_in, const int* in_sizes, int n_in,
                              void* d_out, int out_size, void* d_ws, size_t ws_size,
                              hipStream_t stream)
{
    const int S = 120, T = 10, B = 128, E = 80, HW = 75, HS = 700, V = 30000;
    const int Nw = S * B;            // 15360
    const int Gw = 3 * HW;           // 225
    const int Gs = 3 * HS;           // 2100
    (void)in_sizes; (void)n_in; (void)out_size; (void)ws_size;

    const int*   x       = (const int*)d_in[0];
    const float* emb     = (const float*)d_in[1];
    const float* we_Wih0 = (const float*)d_in[2],  *we_Whh0 = (const float*)d_in[3];
    const float* we_bih0 = (const float*)d_in[4],  *we_bhh0 = (const float*)d_in[5];
    const float* we_Wih1 = (const float*)d_in[6],  *we_Whh1 = (const float*)d_in[7];
    const float* we_bih1 = (const float*)d_in[8],  *we_bhh1 = (const float*)d_in[9];
    const float* se_Wih0 = (const float*)d_in[10], *se_Whh0 = (const float*)d_in[11];
    const float* se_bih0 = (const float*)d_in[12], *se_bhh0 = (const float*)d_in[13];
    const float* se_Wih1 = (const float*)d_in[14], *se_Whh1 = (const float*)d_in[15];
    const float* se_bih1 = (const float*)d_in[16], *se_bhh1 = (const float*)d_in[17];

    // ---- arena (132.0 MB total; proven-safe < 142.2 MB) ----
    char* ws = (char*)d_ws;
    const size_t oP1 = 9340000;                  // words bf16 [Nw,304] = 9,338,880
    const size_t oP2 = oP1 + 49152000;           // y0w [10,Nw,160]b | y0s [Nw,1408]b
    const size_t oP3 = oP2 + 43008000;           // embW 27MB | bufL0+bufL1 43MB
    const size_t total = oP3 + 30516480;         // 132,016,480

    // word-phase pointers
    bf16*  words  = (bf16*)ws;
    bf16*  y0w    = (bf16*)(ws + oP1);
    bf16*  embW   = (bf16*)(ws + oP2);
    float* h_w0   = (float*)(ws + oP3);
    float* h_w1   = (float*)(ws + oP3 + 9216000);
    bf16*  pingW  = (bf16*)(ws + oP3 + 18432000);        // 2 x 5,898,240 B
    bf16*  Whh0bw = (bf16*)(ws + oP3 + 30228480);        // [2,225,80]
    bf16*  Whh1bw = (bf16*)(ws + oP3 + 30300480);
    bf16*  Wih1pw = (bf16*)(ws + oP3 + 30372480);        // [2,225,160]
    const long PWE = 2L * Nw * 96;                       // ping stride elems
    // sentence-phase overlays
    bf16*  y0s    = (bf16*)(ws + oP1);                   // [Nw,1408]
    bf16*  bufL0  = (bf16*)(ws + oP2);                   // [2,20,128,2100]
    bf16*  bufL1  = (bf16*)(ws + oP2 + 21504000);
    bf16*  Whh0b  = (bf16*)(ws + oP3);                   // [2,2100,700]
    bf16*  Whh1b  = (bf16*)(ws + oP3 + 5880000);
    bf16*  hbf0   = (bf16*)(ws + oP3 + 11760000);        // 2 pings x 358,400
    bf16*  hbf1   = (bf16*)(ws + oP3 + 12476800);
    float* h_s0   = (float*)(ws + oP3 + 13193600);
    float* h_s1   = (float*)(ws + oP3 + 13910400);
    bf16*  Wih0p  = (bf16*)(ws + oP3 + 14627200);        // [2,2176,304]
    bf16*  Wih1p  = (bf16*)(ws + oP3 + 17273216);        // [2,2176,1408]

    // Targeted memsets: embW/bufL region (43MB) is fully written before any
    // read; everything else (pads, h states, weight pad rows) zeroed here.
    hipMemsetAsync(ws, 0, oP2, stream);                  // words pads + y0w/y0s holes
    hipMemsetAsync(ws + oP3, 0, 30516480, stream);       // h_w*, pingW, wts (pad rows)

    // ===================== word encoder =====================
    // embW[d] = emb @ Wih0[d]^T : [V,80] @ [225,80]^T -> [2,V,225]
    gemm_mfma<<<dim3((Gw + MBN - 1) / MBN, (V + MBM - 1) / MBM, 2), 256, 0, stream>>>(
        emb, 0, we_Wih0, (long)Gw * E, embW, (long)V * Gw, V, Gw, E);
    // weight prep (bf16, padded)
    for (int d = 0; d < 2; ++d) {
        f2bpad<<<(225 * 80 + 255) / 256, 256, 0, stream>>>(
            we_Whh0 + (long)d * 225 * 75, Whh0bw + (long)d * 225 * 80, 225, 75, 80);
        f2bpad<<<(225 * 80 + 255) / 256, 256, 0, stream>>>(
            we_Whh1 + (long)d * 225 * 75, Whh1bw + (long)d * 225 * 80, 225, 75, 80);
        f2bremap<<<(225 * 160 + 255) / 256, 256, 0, stream>>>(
            we_Wih1 + (long)d * 225 * 150, Wih1pw + (long)d * 225 * 160, 225);
    }
    dim3 wgrid(5, Nw / 128, 2);
    // ---- layer 0 ----
    for (int k = 0; k < T; ++k) {
        int p = k & 1;
        gru_word0_fused<<<wgrid, 512, 0, stream>>>(
            x, embW, Whh0bw, we_bih0, we_bhh0,
            pingW + (long)p * PWE, pingW + (long)(p ^ 1) * PWE, h_w0, y0w, T, k);
    }
    hipMemsetAsync(pingW, 0, 11796480, stream);    // re-zero both pings for layer 1
    // ---- layer 1 ----
    for (int k = 0; k < T; ++k) {
        int p = k & 1;
        gru_word1_fused<<<wgrid, 512, 0, stream>>>(
            y0w, Wih1pw, Whh1bw, we_bih1, we_bhh1,
            pingW + (long)p * PWE, pingW + (long)(p ^ 1) * PWE, h_w1, T, k);
    }
    {
        long tot = (long)Nw * 4 * HW;
        concat4<bf16><<<(tot + 255) / 256, 256, 0, stream>>>(h_w0, h_w1, words, Nw, HW, 304);
    }

    // ===================== sentence encoder =====================
    {
        long nwh = 2LL * Gs * HS;
        f2b<<<(nwh + 255) / 256, 256, 0, stream>>>(se_Whh0, Whh0b, nwh);
        f2b<<<(nwh + 255) / 256, 256, 0, stream>>>(se_Whh1, Whh1b, nwh);
        for (int d = 0; d < 2; ++d) {
            f2bpad<<<((long)2100 * 304 + 255) / 256, 256, 0, stream>>>(
                se_Wih0 + (long)d * 2100 * 300, Wih0p + (long)d * 2176 * 304, 2100, 300, 304);
            f2bpad<<<((long)2100 * 1408 + 255) / 256, 256, 0, stream>>>(
                se_Wih1 + (long)d * 2100 * 1400, Wih1p + (long)d * 2176 * 1408, 2100, 1400, 1408);
        }
    }
    hipMemsetAsync(ws + oP3 + 11760000, 0, 2867200, stream);  // hbf0,hbf1,h_s0,h_s1

    const unsigned ldsBytes = (unsigned)(NKS * 3 * 64 * 8 * sizeof(bf16)); // 67,584
    const int C2 = 20, NC = 6;   // pipeline: slot t = l0 chunk t + l1 chunk t-1
    const int nblk = ((Gs + 127) / 128) * ((C2 * B) / 128);   // 17*20 = 340

    for (int t = 0; t <= NC; ++t) {
        if (t < NC) {               // l0 xw for chunk t (KP=304)
            int tb0 = t * C2, tb1 = S - t * C2 - C2;
            gemm_bt<<<dim3(nblk, 1, 2), 256, 0, stream>>>(
                words + (long)tb0 * B * 304, (long)(tb1 - tb0) * B * 304,
                Wih0p, (long)2176 * 304,
                bufL0, (long)C2 * B * Gs, C2 * B, Gs, 304);
        }
        if (t >= 1) {               // l1 xw for chunk t-1 (KP=1408)
            int c = t - 1, tb0 = c * C2, tb1 = S - c * C2 - C2;
            gemm_bt<<<dim3(nblk, 1, 2), 256, 0, stream>>>(
                y0s + (long)tb0 * B * 1408, (long)(tb1 - tb0) * B * 1408,
                Wih1p, (long)2176 * 1408,
                bufL1, (long)C2 * B * Gs, C2 * B, Gs, 1408);
        }
        for (int i = 0; i < C2; ++i) {
            StepJob jobs[2]; int nj = 0;
            if (t < NC) {           // layer-0 job, chunk t
                int k = t * C2 + i;
                StepJob J;
                J.Whh = Whh0b; J.xw = bufL0; J.bih = se_bih0; J.bhh = se_bhh0;
                J.h = h_s0;
                int p = k & 1;
                J.hr = hbf0 + (long)p * HBPE; J.hw = hbf0 + (long)(p ^ 1) * HBPE;
                J.y = y0s;
                J.te0 = k; J.te1 = S - 1 - k; J.tl0 = i; J.tl1 = C2 - 1 - i;
                jobs[nj++] = J;
            }
            if (t >= 1) {           // layer-1 job, chunk t-1
                int k = (t - 1) * C2 + i;
                StepJob J;
                J.Whh = Whh1b; J.xw = bufL1; J.bih = se_bih1; J.bhh = se_bhh1;
                J.h = h_s1;
                int p = k & 1;
                J.hr = hbf1 + (long)p * HBPE; J.hw = hbf1 + (long)(p ^ 1) * HBPE;
                J.y = nullptr;
                J.te0 = k; J.te1 = S - 1 - k; J.tl0 = i; J.tl1 = C2 - 1 - i;
                jobs[nj++] = J;
            }
            if (nj == 1) jobs[1] = jobs[0];
            gru_step_sent2<<<dim3(44, nj, 2), 512, ldsBytes, stream>>>(
                jobs[0], jobs[1], C2);
        }
    }

    // out[1, B, 4*HS] = [sf0 | sb0 | sf1 | sb1]  (float32)
    {
        long tot = (long)B * 4 * HS;
        concat4<float><<<(tot + 255) / 256, 256, 0, stream>>>(
            h_s0, h_s1, (float*)d_out, B, HS, 4 * HS);
    }
}